// Round 6
// baseline (11895.490 us; speedup 1.0000x reference)
//
#include <hip/hip_runtime.h>
#include <cstddef>

constexpr int kB = 2;
constexpr int kN = 16384;
constexpr int kC = 64;
constexpr int kS = 4096;   // NPOINT
constexpr int kNS = 32;    // NSAMPLE
constexpr int kNC = 256;   // chunks per batch (64 points each)

__device__ __forceinline__ unsigned expand10(unsigned v) {
  v &= 1023u;
  v = (v | (v << 16)) & 0x030000FFu;
  v = (v | (v <<  8)) & 0x0300F00Fu;
  v = (v | (v <<  4)) & 0x030C30C3u;
  v = (v | (v <<  2)) & 0x09249249u;
  return v;
}

// -------- transpose [b][Cdim][Ndim] -> [b][Ndim][Cdim], 32x32 tiles --------
__global__ void transpose_kernel(const float* __restrict__ in,
                                 float* __restrict__ out,
                                 int Cdim, int Ndim) {
  __shared__ float tile[32][33];
  int b = blockIdx.z;
  int n0 = blockIdx.x * 32;
  int c0 = blockIdx.y * 32;
  int tx = threadIdx.x;
  const float* inb = in + (size_t)b * Cdim * Ndim;
  float* outb = out + (size_t)b * Cdim * Ndim;
#pragma unroll
  for (int i = threadIdx.y; i < 32; i += 8)
    tile[i][tx] = inb[(size_t)(c0 + i) * Ndim + (n0 + tx)];
  __syncthreads();
#pragma unroll
  for (int i = threadIdx.y; i < 32; i += 8)
    outb[(size_t)(n0 + i) * Cdim + (c0 + tx)] = tile[tx][i];
}

// -------- FPS prep: bbox -> morton -> in-LDS bitonic sort -> SoA + chunk meta.
// Sort/meta quality only affects SPEED of fps pruning, never correctness
// (any bijection + conservative radii is exact).
__global__ __launch_bounds__(1024) void fps_prep_kernel(
    const float* __restrict__ xyz, float* __restrict__ xs, float* __restrict__ ys,
    float* __restrict__ zs, int* __restrict__ sorted_orig,
    float* __restrict__ ctr, float* __restrict__ rad) {
  const int b = blockIdx.x;
  const int t = threadIdx.x;
  const int lane = t & 63;
  const int w = t >> 6;
  const float* P = xyz + (size_t)b * kN * 3;
  __shared__ unsigned long long keys[kN];   // 128 KB
  __shared__ float sbb[6][16];

  // bbox
  float mnx = 3e38f, mny = 3e38f, mnz = 3e38f;
  float mxx = -3e38f, mxy = -3e38f, mxz = -3e38f;
  for (int p = t; p < kN; p += 1024) {
    float x = P[p * 3], y = P[p * 3 + 1], z = P[p * 3 + 2];
    mnx = fminf(mnx, x); mny = fminf(mny, y); mnz = fminf(mnz, z);
    mxx = fmaxf(mxx, x); mxy = fmaxf(mxy, y); mxz = fmaxf(mxz, z);
  }
#pragma unroll
  for (int off = 32; off >= 1; off >>= 1) {
    mnx = fminf(mnx, __shfl_xor(mnx, off, 64));
    mny = fminf(mny, __shfl_xor(mny, off, 64));
    mnz = fminf(mnz, __shfl_xor(mnz, off, 64));
    mxx = fmaxf(mxx, __shfl_xor(mxx, off, 64));
    mxy = fmaxf(mxy, __shfl_xor(mxy, off, 64));
    mxz = fmaxf(mxz, __shfl_xor(mxz, off, 64));
  }
  if (lane == 0) {
    sbb[0][w] = mnx; sbb[1][w] = mny; sbb[2][w] = mnz;
    sbb[3][w] = mxx; sbb[4][w] = mxy; sbb[5][w] = mxz;
  }
  __syncthreads();
  mnx = sbb[0][lane & 15]; mny = sbb[1][lane & 15]; mnz = sbb[2][lane & 15];
  mxx = sbb[3][lane & 15]; mxy = sbb[4][lane & 15]; mxz = sbb[5][lane & 15];
#pragma unroll
  for (int off = 8; off >= 1; off >>= 1) {
    mnx = fminf(mnx, __shfl_xor(mnx, off, 64));
    mny = fminf(mny, __shfl_xor(mny, off, 64));
    mnz = fminf(mnz, __shfl_xor(mnz, off, 64));
    mxx = fmaxf(mxx, __shfl_xor(mxx, off, 64));
    mxy = fmaxf(mxy, __shfl_xor(mxy, off, 64));
    mxz = fmaxf(mxz, __shfl_xor(mxz, off, 64));
  }
  __syncthreads();
  // morton keys: (morton30 << 14) | orig_idx
  const float sx = 1023.0f / fmaxf(mxx - mnx, 1e-20f);
  const float sy = 1023.0f / fmaxf(mxy - mny, 1e-20f);
  const float sz = 1023.0f / fmaxf(mxz - mnz, 1e-20f);
  for (int p = t; p < kN; p += 1024) {
    float x = P[p * 3], y = P[p * 3 + 1], z = P[p * 3 + 2];
    int qx = (int)((x - mnx) * sx); qx = max(0, min(1023, qx));
    int qy = (int)((y - mny) * sy); qy = max(0, min(1023, qy));
    int qz = (int)((z - mnz) * sz); qz = max(0, min(1023, qz));
    unsigned mort = (expand10((unsigned)qx) << 2) |
                    (expand10((unsigned)qy) << 1) | expand10((unsigned)qz);
    keys[p] = ((unsigned long long)mort << 14) | (unsigned)p;
  }
  __syncthreads();
  // bitonic sort, 105 substages
  for (unsigned k = 2; k <= (unsigned)kN; k <<= 1) {
    for (unsigned j = k >> 1; j > 0; j >>= 1) {
      for (int i = t; i < kN; i += 1024) {
        int l = i ^ (int)j;
        if (l > i) {
          unsigned long long a = keys[i], c = keys[l];
          bool asc = ((i & (int)k) == 0);
          if ((a > c) == asc) { keys[i] = c; keys[l] = a; }
        }
      }
      __syncthreads();
    }
  }
  // permuted SoA
  float* XS = xs + (size_t)b * kN;
  float* YS = ys + (size_t)b * kN;
  float* ZS = zs + (size_t)b * kN;
  int* OG = sorted_orig + (size_t)b * kN;
  for (int i = t; i < kN; i += 1024) {
    int o = (int)(keys[i] & 0x3FFFull);
    XS[i] = P[o * 3]; YS[i] = P[o * 3 + 1]; ZS[i] = P[o * 3 + 2];
    OG[i] = o;
  }
  // chunk meta (bounding sphere, conservatively inflated)
  if (t < kNC) {
    float amn = 3e38f, bmn = 3e38f, cmn = 3e38f;
    float amx = -3e38f, bmx = -3e38f, cmx = -3e38f;
    for (int kk = 0; kk < 64; kk++) {
      int o = (int)(keys[t * 64 + kk] & 0x3FFFull);
      float x = P[o * 3], y = P[o * 3 + 1], z = P[o * 3 + 2];
      amn = fminf(amn, x); amx = fmaxf(amx, x);
      bmn = fminf(bmn, y); bmx = fmaxf(bmx, y);
      cmn = fminf(cmn, z); cmx = fmaxf(cmx, z);
    }
    float ux = (amn + amx) * 0.5f, uy = (bmn + bmx) * 0.5f, uz = (cmn + cmx) * 0.5f;
    float hx = (amx - amn) * 0.5f, hy = (bmx - bmn) * 0.5f, hz = (cmx - cmn) * 0.5f;
    float r = sqrtf(hx * hx + hy * hy + hz * hz) * 1.0002f + 1e-6f;
    ctr[((size_t)b * kNC + t) * 3 + 0] = ux;
    ctr[((size_t)b * kNC + t) * 3 + 1] = uy;
    ctr[((size_t)b * kNC + t) * 3 + 2] = uz;
    rad[(size_t)b * kNC + t] = r;
  }
}

// -------- farthest point sampling v6: chunked with exact geometric pruning --
// 16 waves; chunk c owned by wave (c & 15) (spatial neighbors -> different
// waves). Per iter: 16 prune tests per wave in one vector pass -> process
// only failing chunks (exact numpy RNE math, (value desc, orig asc) ties);
// skipped chunks provably unchanged: (du - r - 1e-5)^2 >= M*1.00001 implies
// d(p,c) >= dist[p] for every p in chunk. dist/orig planes + chunk maxima
// live in LDS (134 KB).
__global__ __launch_bounds__(1024) void fps_kernel(
    const float* __restrict__ xyz,
    const float* __restrict__ xs, const float* __restrict__ ys,
    const float* __restrict__ zs, const int* __restrict__ sorted_orig,
    const float* __restrict__ ctr, const float* __restrict__ rad,
    float* __restrict__ new_xyz) {
  const int b = blockIdx.x;
  const int t = threadIdx.x;
  const int lane = t & 63;
  const int w = t >> 6;
  const float* P = xyz + (size_t)b * kN * 3;
  const float* X = xs + (size_t)b * kN;
  const float* Y = ys + (size_t)b * kN;
  const float* Z = zs + (size_t)b * kN;
  const int* OG = sorted_orig + (size_t)b * kN;

  __shared__ float dist[kN];     // 64 KB
  __shared__ int sorig[kN];      // 64 KB
  __shared__ float M[kNC];
  __shared__ int A[kNC];
  __shared__ float cux[kNC], cuy[kNC], cuz[kNC], crad[kNC];

  for (int i = t; i < kN; i += 1024) { dist[i] = 1e10f; sorig[i] = OG[i]; }
  if (t < kNC) {
    M[t] = 1e10f; A[t] = 0;
    cux[t] = ctr[((size_t)b * kNC + t) * 3 + 0];
    cuy[t] = ctr[((size_t)b * kNC + t) * 3 + 1];
    cuz[t] = ctr[((size_t)b * kNC + t) * 3 + 2];
    crad[t] = rad[(size_t)b * kNC + t];
  }
  __syncthreads();

  float cx = P[0], cy = P[1], cz = P[2];

  for (int it = 0; it < kS; ++it) {
    if (t == 0) {
      float* o = new_xyz + ((size_t)b * kS + it) * 3;
      o[0] = cx; o[1] = cy; o[2] = cz;
    }
    // prune tests: lane k (k<16) tests chunk (k<<4)|w
    {
      int c = ((lane & 15) << 4) | w;
      float dxu = cx - cux[c], dyu = cy - cuy[c], dzu = cz - cuz[c];
      float du = sqrtf(dxu * dxu + dyu * dyu + dzu * dzu);
      float lb = du - crad[c] - 1e-5f;
      bool skip = (lb > 0.0f) && (lb * lb >= M[c] * 1.00001f);
      unsigned long long bal = __ballot((!skip) && (lane < 16));
      unsigned fmask = (unsigned)bal & 0xFFFFu;
      while (fmask) {
        int k2 = __ffs(fmask) - 1;
        fmask &= fmask - 1;
        int c2 = (k2 << 4) | w;
        int p = (c2 << 6) | lane;
        float xx = X[p], yy = Y[p], zz = Z[p];
        float ddx = cx - xx, ddy = cy - yy, ddz = cz - zz;   // sign-flipped sub; square identical
        float d = __fadd_rn(__fadd_rn(__fmul_rn(ddx, ddx), __fmul_rn(ddy, ddy)),
                            __fmul_rn(ddz, ddz));
        float dk = fminf(dist[p], d);
        dist[p] = dk;
        float bk = dk;
#pragma unroll
        for (int off = 32; off >= 1; off >>= 1) bk = fmaxf(bk, __shfl_xor(bk, off, 64));
        unsigned long long mm = __ballot(dk == bk);
        int o;
        if (__popcll(mm) == 1) {
          o = sorig[(c2 << 6) | (int)(__ffsll(mm) - 1)];
        } else {  // rare exact tie: min orig among maxima
          int oo = (dk == bk) ? sorig[p] : 0x7fffffff;
#pragma unroll
          for (int off = 32; off >= 1; off >>= 1) oo = min(oo, __shfl_xor(oo, off, 64));
          o = oo;
        }
        if (lane == 0) { M[c2] = bk; A[c2] = o; }
      }
    }
    __syncthreads();
    // global argmax over chunk maxima; ties -> min orig idx (numpy first-max)
    float v0 = M[lane], v1 = M[lane + 64], v2 = M[lane + 128], v3 = M[lane + 192];
    float bv = fmaxf(fmaxf(v0, v1), fmaxf(v2, v3));
#pragma unroll
    for (int off = 32; off >= 1; off >>= 1) bv = fmaxf(bv, __shfl_xor(bv, off, 64));
    int aa = 0x7fffffff;
    if (v0 == bv) aa = A[lane];
    if (v1 == bv) aa = min(aa, A[lane + 64]);
    if (v2 == bv) aa = min(aa, A[lane + 128]);
    if (v3 == bv) aa = min(aa, A[lane + 192]);
#pragma unroll
    for (int off = 32; off >= 1; off >>= 1) aa = min(aa, __shfl_xor(aa, off, 64));
    const int far = __builtin_amdgcn_readfirstlane(aa);
    cx = P[far * 3]; cy = P[far * 3 + 1]; cz = P[far * 3 + 2];
    __syncthreads();   // M/A reads (above) vs next-iter writes
  }
}

// -------- ball query: one wave per query, first-32 ascending indices --------
__global__ __launch_bounds__(256) void ball_query_kernel(const float* __restrict__ xyz,
                                                         const float* __restrict__ new_xyz,
                                                         int* __restrict__ idx) {
  const int q = (int)((blockIdx.x * 256 + threadIdx.x) >> 6);
  const int lane = threadIdx.x & 63;
  const int b = q >> 12;
  const float* P = xyz + (size_t)b * kN * 3;
  const float qx = new_xyz[q * 3 + 0];
  const float qy = new_xyz[q * 3 + 1];
  const float qz = new_xyz[q * 3 + 2];
  int cnt = 0;
  int first = -1;
  const int base = q * kNS;
  for (int j = 0; j < kN / 64; j++) {
    const int p = (j << 6) + lane;
    float dx = P[p * 3 + 0] - qx;
    float dy = P[p * 3 + 1] - qy;
    float dz = P[p * 3 + 2] - qz;
    float d = __fadd_rn(__fadd_rn(__fmul_rn(dx, dx), __fmul_rn(dy, dy)),
                        __fmul_rn(dz, dz));
    bool inb = d < 0.25f;
    unsigned long long m = __ballot(inb);
    if (first < 0 && m != 0ull) first = (j << 6) + (__ffsll(m) - 1);
    if (inb && cnt < kNS) {
      int r = cnt + (int)__popcll(m & ((1ull << lane) - 1ull));
      if (r < kNS) idx[base + r] = p;
    }
    cnt += (int)__popcll(m);
    if (cnt >= kNS) break;
  }
  if (cnt < kNS) {
    int fill = (first >= 0) ? first : 0;
    if (lane >= cnt && lane < kNS) idx[base + lane] = fill;
  }
}

// -------- gather + MLP(67->64->64->128) + maxpool + agg(128->128) + score ----
__global__ __launch_bounds__(128) void group_mlp_kernel(
    const float* __restrict__ xyz, const float* __restrict__ new_xyz,
    const float* __restrict__ featsT, const int* __restrict__ nidx,
    const float* __restrict__ w1, const float* __restrict__ b1,
    const float* __restrict__ w2, const float* __restrict__ b2,
    const float* __restrict__ w3, const float* __restrict__ b3,
    const float* __restrict__ wa, const float* __restrict__ ba,
    const float* __restrict__ wc, const float* __restrict__ bc,
    float* __restrict__ aggT, float* __restrict__ scores) {
  __shared__ float smem[2 * 4384];
  const int wid = threadIdx.x >> 6;
  const int lane = threadIdx.x & 63;
  const int q = blockIdx.x * 2 + wid;
  const int b = q >> 12;
  float* Xs = smem + wid * 4384;   // [32][68] input; later reused as H2 [32][64]
  float* H1 = Xs + 32 * 68;        // [32][64]
  float* pool = H1 + 32 * 64;      // [128]
  int* idxs = (int*)(pool + 128);  // [32]

  if (lane < 32) idxs[lane] = nidx[q * kNS + lane];
  const float qx = new_xyz[q * 3 + 0];
  const float qy = new_xyz[q * 3 + 1];
  const float qz = new_xyz[q * 3 + 2];
  __syncthreads();

  const float* P = xyz + (size_t)b * kN * 3;
  const float* F = featsT + (size_t)b * kN * kC;
  if (lane < 32) {
    int p = idxs[lane];
    Xs[lane * 68 + 0] = P[p * 3 + 0] - qx;
    Xs[lane * 68 + 1] = P[p * 3 + 1] - qy;
    Xs[lane * 68 + 2] = P[p * 3 + 2] - qz;
  } else {
    Xs[(lane - 32) * 68 + 67] = 0.0f;   // pad column
  }
  for (int j = 0; j < 32; j++) {
    Xs[j * 68 + 3 + lane] = F[(size_t)idxs[j] * kC + lane];
  }
  __syncthreads();

  float w[68];
  // ---- layer 1: 67 -> 64, lane = out channel ----
  {
    const int o = lane;
#pragma unroll
    for (int k = 0; k < 67; k++) w[k] = w1[o * 67 + k];
    w[67] = 0.0f;
    const float bias = b1[o];
    for (int r = 0; r < 32; r++) {
      float acc = bias;
#pragma unroll
      for (int k4 = 0; k4 < 17; k4++) {
        float4 x = *(const float4*)&Xs[r * 68 + k4 * 4];
        acc += x.x * w[k4 * 4 + 0] + x.y * w[k4 * 4 + 1] +
               x.z * w[k4 * 4 + 2] + x.w * w[k4 * 4 + 3];
      }
      H1[r * 64 + o] = fmaxf(acc, 0.0f);
    }
  }
  __syncthreads();
  // ---- layer 2: 64 -> 64, write H2 into Xs region ----
  {
    const int o = lane;
#pragma unroll
    for (int k = 0; k < 64; k++) w[k] = w2[o * 64 + k];
    const float bias = b2[o];
    for (int r = 0; r < 32; r++) {
      float acc = bias;
#pragma unroll
      for (int k4 = 0; k4 < 16; k4++) {
        float4 x = *(const float4*)&H1[r * 64 + k4 * 4];
        acc += x.x * w[k4 * 4 + 0] + x.y * w[k4 * 4 + 1] +
               x.z * w[k4 * 4 + 2] + x.w * w[k4 * 4 + 3];
      }
      Xs[r * 64 + o] = fmaxf(acc, 0.0f);
    }
  }
  __syncthreads();
  // ---- layer 3: 64 -> 128 (2 out channels per lane) + maxpool over rows ----
  {
    const int c = lane;
    float wB[64];
#pragma unroll
    for (int k = 0; k < 64; k++) {
      w[k] = w3[c * 64 + k];
      wB[k] = w3[(c + 64) * 64 + k];
    }
    const float biasA = b3[c];
    const float biasB = b3[c + 64];
    float pa = 0.0f, pb = 0.0f;   // relu folded: max over relu(h) == max(0, max h)
    for (int r = 0; r < 32; r++) {
      float a = biasA, bb = biasB;
#pragma unroll
      for (int k4 = 0; k4 < 16; k4++) {
        float4 x = *(const float4*)&Xs[r * 64 + k4 * 4];
        a  += x.x * w[k4 * 4 + 0] + x.y * w[k4 * 4 + 1] +
              x.z * w[k4 * 4 + 2] + x.w * w[k4 * 4 + 3];
        bb += x.x * wB[k4 * 4 + 0] + x.y * wB[k4 * 4 + 1] +
              x.z * wB[k4 * 4 + 2] + x.w * wB[k4 * 4 + 3];
      }
      pa = fmaxf(pa, a);
      pb = fmaxf(pb, bb);
    }
    pool[c] = pa;
    pool[c + 64] = pb;
  }
  __syncthreads();
  // ---- aggregation 128->128 + relu, confidence 128->1 ----
  {
    const int c = lane;
    float accA = ba[c], accB = ba[c + 64];
#pragma unroll
    for (int k4 = 0; k4 < 32; k4++) {
      float4 pv = *(const float4*)&pool[k4 * 4];
      float4 wva = *(const float4*)&wa[c * 128 + k4 * 4];
      float4 wvb = *(const float4*)&wa[(c + 64) * 128 + k4 * 4];
      accA += pv.x * wva.x + pv.y * wva.y + pv.z * wva.z + pv.w * wva.w;
      accB += pv.x * wvb.x + pv.y * wvb.y + pv.z * wvb.z + pv.w * wvb.w;
    }
    float aggA = fmaxf(accA, 0.0f);
    float aggB = fmaxf(accB, 0.0f);
    aggT[(size_t)q * 128 + c] = aggA;
    aggT[(size_t)q * 128 + 64 + c] = aggB;
    float partial = aggA * wc[c] + aggB * wc[c + 64];
#pragma unroll
    for (int off = 32; off >= 1; off >>= 1) partial += __shfl_xor(partial, off, 64);
    if (lane == 0) scores[q] = partial + bc[0];
  }
}

extern "C" void kernel_launch(void* const* d_in, const int* in_sizes, int n_in,
                              void* d_out, int out_size, void* d_ws, size_t ws_size,
                              hipStream_t stream) {
  const float* xyz   = (const float*)d_in[0];
  const float* feats = (const float*)d_in[1];
  const float* w1 = (const float*)d_in[2];
  const float* b1 = (const float*)d_in[3];
  const float* w2 = (const float*)d_in[4];
  const float* b2 = (const float*)d_in[5];
  const float* w3 = (const float*)d_in[6];
  const float* b3 = (const float*)d_in[7];
  const float* wa = (const float*)d_in[8];
  const float* ba = (const float*)d_in[9];
  const float* wc = (const float*)d_in[10];
  const float* bc = (const float*)d_in[11];

  float* out_new_xyz = (float*)d_out;                               // B*S*3
  float* out_feat    = out_new_xyz + (size_t)kB * kS * 3;           // B*128*S
  float* out_scores  = out_feat + (size_t)kB * 128 * kS;            // B*S

  // ws layout: featsT [0,8MiB), idx [8MiB,9MiB), aggT [9MiB,13MiB).
  // FPS-prep buffers ALIAS the aggT region (xs/ys/zs/orig/ctr/rad, ~560KB):
  // they are consumed by fps_kernel strictly BEFORE group_mlp writes aggT.
  char* ws = (char*)d_ws;
  float* featsT = (float*)ws;
  int*   idxbuf = (int*)(ws + (size_t)8 * 1024 * 1024);
  float* aggT   = (float*)(ws + (size_t)9 * 1024 * 1024);
  float* xsb = (float*)(ws + (size_t)9 * 1024 * 1024);               // 2*64KB
  float* ysb = (float*)(ws + (size_t)9 * 1024 * 1024 + 128 * 1024);
  float* zsb = (float*)(ws + (size_t)9 * 1024 * 1024 + 256 * 1024);
  int*   ogb = (int*)  (ws + (size_t)9 * 1024 * 1024 + 384 * 1024);  // 2*64KB
  float* ctrb = (float*)(ws + (size_t)9 * 1024 * 1024 + 512 * 1024); // 6KB
  float* radb = (float*)(ws + (size_t)9 * 1024 * 1024 + 544 * 1024); // 2KB

  // features (B,C,N) -> featsT (B,N,C)
  transpose_kernel<<<dim3(kN / 32, kC / 32, kB), dim3(32, 8, 1), 0, stream>>>(
      feats, featsT, kC, kN);
  // FPS prep: morton sort + chunk metadata
  fps_prep_kernel<<<dim3(kB), dim3(1024), 0, stream>>>(
      xyz, xsb, ysb, zsb, ogb, ctrb, radb);
  // FPS -> new_xyz (chunk-pruned, exact)
  fps_kernel<<<dim3(kB), dim3(1024), 0, stream>>>(
      xyz, xsb, ysb, zsb, ogb, ctrb, radb, out_new_xyz);
  // ball query -> idx
  ball_query_kernel<<<dim3(kB * kS / 4), dim3(256), 0, stream>>>(
      xyz, out_new_xyz, idxbuf);
  // gather + MLPs + pool + agg + scores
  group_mlp_kernel<<<dim3(kB * kS / 2), dim3(128), 0, stream>>>(
      xyz, out_new_xyz, featsT, idxbuf,
      w1, b1, w2, b2, w3, b3, wa, ba, wc, bc, aggT, out_scores);
  // aggT (B,S,128) -> new_features (B,128,S)
  transpose_kernel<<<dim3(128 / 32, kS / 32, kB), dim3(32, 8, 1), 0, stream>>>(
      aggT, out_feat, kS, 128);
}

// Round 7
// 9221.605 us; speedup vs baseline: 1.2900x; 1.2900x over previous
//
#include <hip/hip_runtime.h>
#include <cstddef>

constexpr int kB = 2;
constexpr int kN = 16384;
constexpr int kC = 64;
constexpr int kS = 4096;   // NPOINT
constexpr int kNS = 32;    // NSAMPLE
constexpr int kNC = 256;   // chunks per batch (64 points each)

__device__ __forceinline__ unsigned expand10(unsigned v) {
  v &= 1023u;
  v = (v | (v << 16)) & 0x030000FFu;
  v = (v | (v <<  8)) & 0x0300F00Fu;
  v = (v | (v <<  4)) & 0x030C30C3u;
  v = (v | (v <<  2)) & 0x09249249u;
  return v;
}

// ---- DPP wave64 reductions (rocPRIM pattern): 6 VALU steps, result lane 63.
// Formulated as op(x, dpp(x)) so invalid-lane fill (0 or old) never corrupts:
// fill is always dominated for our operand ranges (values >= 0).
template <int CTRL>
__device__ __forceinline__ float dpp_maxf(float x) {
  int y = __builtin_amdgcn_update_dpp(__float_as_int(x), __float_as_int(x),
                                      CTRL, 0xF, 0xF, false);
  return fmaxf(x, __int_as_float(y));
}
template <int CTRL>
__device__ __forceinline__ int dpp_maxi(int x) {
  int y = __builtin_amdgcn_update_dpp(x, x, CTRL, 0xF, 0xF, false);
  return max(x, y);
}
__device__ __forceinline__ float wave_max_f32(float x) {
  x = dpp_maxf<0xB1>(x);    // quad_perm [1,0,3,2]
  x = dpp_maxf<0x4E>(x);    // quad_perm [2,3,0,1]
  x = dpp_maxf<0x114>(x);   // row_shr:4
  x = dpp_maxf<0x118>(x);   // row_shr:8
  x = dpp_maxf<0x142>(x);   // row_bcast:15
  x = dpp_maxf<0x143>(x);   // row_bcast:31
  return __int_as_float(__builtin_amdgcn_readlane(__float_as_int(x), 63));
}
__device__ __forceinline__ int wave_max_i32(int x) {
  x = dpp_maxi<0xB1>(x);
  x = dpp_maxi<0x4E>(x);
  x = dpp_maxi<0x114>(x);
  x = dpp_maxi<0x118>(x);
  x = dpp_maxi<0x142>(x);
  x = dpp_maxi<0x143>(x);
  return __builtin_amdgcn_readlane(x, 63);
}
// min over non-negative packed keys; lanes may contribute 0x7FFFFFFF = none
__device__ __forceinline__ int wave_min_pos_i32(int x) {
  return 0x7FFFFFFF - wave_max_i32(0x7FFFFFFF - x);
}
__device__ __forceinline__ float readlane_f(float x, int l) {
  return __int_as_float(__builtin_amdgcn_readlane(__float_as_int(x), l));
}

// -------- transpose [b][Cdim][Ndim] -> [b][Ndim][Cdim], 32x32 tiles --------
__global__ void transpose_kernel(const float* __restrict__ in,
                                 float* __restrict__ out,
                                 int Cdim, int Ndim) {
  __shared__ float tile[32][33];
  int b = blockIdx.z;
  int n0 = blockIdx.x * 32;
  int c0 = blockIdx.y * 32;
  int tx = threadIdx.x;
  const float* inb = in + (size_t)b * Cdim * Ndim;
  float* outb = out + (size_t)b * Cdim * Ndim;
#pragma unroll
  for (int i = threadIdx.y; i < 32; i += 8)
    tile[i][tx] = inb[(size_t)(c0 + i) * Ndim + (n0 + tx)];
  __syncthreads();
#pragma unroll
  for (int i = threadIdx.y; i < 32; i += 8)
    outb[(size_t)(n0 + i) * Cdim + (c0 + tx)] = tile[tx][i];
}

// -------- FPS prep: bbox -> morton -> in-LDS bitonic sort -> SoA + chunk meta.
// Sort/meta quality only affects SPEED of fps pruning, never correctness.
__global__ __launch_bounds__(1024) void fps_prep_kernel(
    const float* __restrict__ xyz, float* __restrict__ xs, float* __restrict__ ys,
    float* __restrict__ zs, int* __restrict__ sorted_orig,
    float* __restrict__ ctr, float* __restrict__ rad) {
  const int b = blockIdx.x;
  const int t = threadIdx.x;
  const int lane = t & 63;
  const int w = t >> 6;
  const float* P = xyz + (size_t)b * kN * 3;
  __shared__ unsigned long long keys[kN];   // 128 KB
  __shared__ float sbb[6][16];

  float mnx = 3e38f, mny = 3e38f, mnz = 3e38f;
  float mxx = -3e38f, mxy = -3e38f, mxz = -3e38f;
  for (int p = t; p < kN; p += 1024) {
    float x = P[p * 3], y = P[p * 3 + 1], z = P[p * 3 + 2];
    mnx = fminf(mnx, x); mny = fminf(mny, y); mnz = fminf(mnz, z);
    mxx = fmaxf(mxx, x); mxy = fmaxf(mxy, y); mxz = fmaxf(mxz, z);
  }
#pragma unroll
  for (int off = 32; off >= 1; off >>= 1) {
    mnx = fminf(mnx, __shfl_xor(mnx, off, 64));
    mny = fminf(mny, __shfl_xor(mny, off, 64));
    mnz = fminf(mnz, __shfl_xor(mnz, off, 64));
    mxx = fmaxf(mxx, __shfl_xor(mxx, off, 64));
    mxy = fmaxf(mxy, __shfl_xor(mxy, off, 64));
    mxz = fmaxf(mxz, __shfl_xor(mxz, off, 64));
  }
  if (lane == 0) {
    sbb[0][w] = mnx; sbb[1][w] = mny; sbb[2][w] = mnz;
    sbb[3][w] = mxx; sbb[4][w] = mxy; sbb[5][w] = mxz;
  }
  __syncthreads();
  mnx = sbb[0][lane & 15]; mny = sbb[1][lane & 15]; mnz = sbb[2][lane & 15];
  mxx = sbb[3][lane & 15]; mxy = sbb[4][lane & 15]; mxz = sbb[5][lane & 15];
#pragma unroll
  for (int off = 8; off >= 1; off >>= 1) {
    mnx = fminf(mnx, __shfl_xor(mnx, off, 64));
    mny = fminf(mny, __shfl_xor(mny, off, 64));
    mnz = fminf(mnz, __shfl_xor(mnz, off, 64));
    mxx = fmaxf(mxx, __shfl_xor(mxx, off, 64));
    mxy = fmaxf(mxy, __shfl_xor(mxy, off, 64));
    mxz = fmaxf(mxz, __shfl_xor(mxz, off, 64));
  }
  __syncthreads();
  const float sx = 1023.0f / fmaxf(mxx - mnx, 1e-20f);
  const float sy = 1023.0f / fmaxf(mxy - mny, 1e-20f);
  const float sz = 1023.0f / fmaxf(mxz - mnz, 1e-20f);
  for (int p = t; p < kN; p += 1024) {
    float x = P[p * 3], y = P[p * 3 + 1], z = P[p * 3 + 2];
    int qx = (int)((x - mnx) * sx); qx = max(0, min(1023, qx));
    int qy = (int)((y - mny) * sy); qy = max(0, min(1023, qy));
    int qz = (int)((z - mnz) * sz); qz = max(0, min(1023, qz));
    unsigned mort = (expand10((unsigned)qx) << 2) |
                    (expand10((unsigned)qy) << 1) | expand10((unsigned)qz);
    keys[p] = ((unsigned long long)mort << 14) | (unsigned)p;
  }
  __syncthreads();
  for (unsigned k = 2; k <= (unsigned)kN; k <<= 1) {
    for (unsigned j = k >> 1; j > 0; j >>= 1) {
      for (int i = t; i < kN; i += 1024) {
        int l = i ^ (int)j;
        if (l > i) {
          unsigned long long a = keys[i], c = keys[l];
          bool asc = ((i & (int)k) == 0);
          if ((a > c) == asc) { keys[i] = c; keys[l] = a; }
        }
      }
      __syncthreads();
    }
  }
  float* XS = xs + (size_t)b * kN;
  float* YS = ys + (size_t)b * kN;
  float* ZS = zs + (size_t)b * kN;
  int* OG = sorted_orig + (size_t)b * kN;
  for (int i = t; i < kN; i += 1024) {
    int o = (int)(keys[i] & 0x3FFFull);
    XS[i] = P[o * 3]; YS[i] = P[o * 3 + 1]; ZS[i] = P[o * 3 + 2];
    OG[i] = o;
  }
  if (t < kNC) {
    float amn = 3e38f, bmn = 3e38f, cmn = 3e38f;
    float amx = -3e38f, bmx = -3e38f, cmx = -3e38f;
    for (int kk = 0; kk < 64; kk++) {
      int o = (int)(keys[t * 64 + kk] & 0x3FFFull);
      float x = P[o * 3], y = P[o * 3 + 1], z = P[o * 3 + 2];
      amn = fminf(amn, x); amx = fmaxf(amx, x);
      bmn = fminf(bmn, y); bmx = fmaxf(bmx, y);
      cmn = fminf(cmn, z); cmx = fmaxf(cmx, z);
    }
    float ux = (amn + amx) * 0.5f, uy = (bmn + bmx) * 0.5f, uz = (cmn + cmx) * 0.5f;
    float hx = (amx - amn) * 0.5f, hy = (bmx - bmn) * 0.5f, hz = (cmx - cmn) * 0.5f;
    float r = sqrtf(hx * hx + hy * hy + hz * hz) * 1.0002f + 1e-6f;
    ctr[((size_t)b * kNC + t) * 3 + 0] = ux;
    ctr[((size_t)b * kNC + t) * 3 + 1] = uy;
    ctr[((size_t)b * kNC + t) * 3 + 2] = uz;
    rad[(size_t)b * kNC + t] = r;
  }
}

// -------- farthest point sampling v7: pruned chunks + DPP reductions --------
// Chunk c=(k<<4)|w owned by wave w, stored at slot s=(w<<4)|k (transposed:
// conflict-free meta reads, wave-local writes). Per iter: prune test (16
// lanes), process failing chunks in ILP-2 pairs; per-chunk max via DPP
// (6 VALU steps, not ds_swizzle); chunk cache {M, A_orig, coords} in LDS.
// Global argmax over 256 slots via DPP; coords of winner from LDS.
// Skipped chunks are provably unchanged; processed chunks use exact numpy
// RNE arithmetic with (value desc, orig-idx asc) tie-breaks.
__global__ __launch_bounds__(1024) void fps_kernel(
    const float* __restrict__ xyz,
    const float* __restrict__ xs, const float* __restrict__ ys,
    const float* __restrict__ zs, const int* __restrict__ sorted_orig,
    const float* __restrict__ ctr, const float* __restrict__ rad,
    float* __restrict__ new_xyz) {
  const int b = blockIdx.x;
  const int t = threadIdx.x;
  const int lane = t & 63;
  const int w = t >> 6;
  const float* P = xyz + (size_t)b * kN * 3;
  const float* X = xs + (size_t)b * kN;
  const float* Y = ys + (size_t)b * kN;
  const float* Z = zs + (size_t)b * kN;
  const int* OG = sorted_orig + (size_t)b * kN;

  __shared__ float dist[kN];        // 64 KB
  __shared__ int sorig[kN];         // 64 KB
  __shared__ float Mv[kNC], CXv[kNC], CYv[kNC], CZv[kNC];
  __shared__ int Av[kNC];
  __shared__ float cux[kNC], cuy[kNC], cuz[kNC], crd[kNC];

  for (int i = t; i < kN; i += 1024) { dist[i] = 1e10f; sorig[i] = OG[i]; }
  if (t < kNC) {
    int sl = ((t & 15) << 4) | (t >> 4);   // chunk t -> slot
    Mv[sl] = 1e10f; Av[sl] = 0;
    CXv[sl] = 0.0f; CYv[sl] = 0.0f; CZv[sl] = 0.0f;
    cux[sl] = ctr[((size_t)b * kNC + t) * 3 + 0];
    cuy[sl] = ctr[((size_t)b * kNC + t) * 3 + 1];
    cuz[sl] = ctr[((size_t)b * kNC + t) * 3 + 2];
    crd[sl] = rad[(size_t)b * kNC + t];
  }
  __syncthreads();

  float cx = P[0], cy = P[1], cz = P[2];

#define FPS_CHUNK_BODY(K)                                                    \
    const int c##K = (k##K << 4) | w;                                        \
    const int p##K = (c##K << 6) | lane;                                     \
    const int s##K = (w << 4) | k##K;                                        \
    const float x##K = X[p##K], y##K = Y[p##K], z##K = Z[p##K];              \
    const float dold##K = dist[p##K];                                        \
    const int o##K = sorig[p##K];

#define FPS_CHUNK_REDUCE(K)                                                  \
    {                                                                        \
      float ddx = cx - x##K, ddy = cy - y##K, ddz = cz - z##K;               \
      float d = __fadd_rn(__fadd_rn(__fmul_rn(ddx, ddx), __fmul_rn(ddy, ddy)),\
                          __fmul_rn(ddz, ddz));                              \
      float dk = fminf(dold##K, d);                                          \
      dist[p##K] = dk;                                                       \
      float bk = wave_max_f32(dk);                                           \
      int po = (dk == bk) ? ((o##K << 6) | lane) : 0x7FFFFFFF;               \
      int pmin = wave_min_pos_i32(po);                                       \
      int wl = pmin & 63;                                                    \
      float ox = readlane_f(x##K, wl);                                       \
      float oy = readlane_f(y##K, wl);                                       \
      float oz = readlane_f(z##K, wl);                                       \
      if (lane == 0) {                                                       \
        Mv[s##K] = bk; Av[s##K] = (pmin >> 6);                               \
        CXv[s##K] = ox; CYv[s##K] = oy; CZv[s##K] = oz;                      \
      }                                                                      \
    }

  for (int it = 0; it < kS; ++it) {
    if (t == 0) {
      float* o = new_xyz + ((size_t)b * kS + it) * 3;
      o[0] = cx; o[1] = cy; o[2] = cz;
    }
    // prune test: lane k tests slot (w<<4)|k  <->  chunk (k<<4)|w
    {
      const int k = lane & 15;
      const int sl = (w << 4) | k;
      float dxu = cx - cux[sl], dyu = cy - cuy[sl], dzu = cz - cuz[sl];
      float du = sqrtf(dxu * dxu + dyu * dyu + dzu * dzu);
      float lb = du - crd[sl] - 1e-5f;
      bool skip = (lb > 0.0f) && (lb * lb >= Mv[sl] * 1.00001f);
      unsigned fmask = (unsigned)__ballot((!skip) && (lane < 16)) & 0xFFFFu;
      while (fmask) {
        const int kA = __ffs(fmask) - 1;
        fmask &= fmask - 1;
        const int kB = fmask ? (__ffs(fmask) - 1) : -1;
        if (kB >= 0) fmask &= fmask - 1;
        FPS_CHUNK_BODY(A)
        if (kB >= 0) {
          FPS_CHUNK_BODY(B)
          FPS_CHUNK_REDUCE(A)
          FPS_CHUNK_REDUCE(B)
        } else {
          FPS_CHUNK_REDUCE(A)
        }
      }
    }
    __syncthreads();
    // global argmax over 256 slots: max value, then min orig-idx among ties
    {
      float v0 = Mv[lane], v1 = Mv[lane + 64], v2 = Mv[lane + 128], v3 = Mv[lane + 192];
      int a0 = Av[lane], a1 = Av[lane + 64], a2 = Av[lane + 128], a3 = Av[lane + 192];
      float bv = wave_max_f32(fmaxf(fmaxf(v0, v1), fmaxf(v2, v3)));
      int pk = 0x7FFFFFFF;
      if (v0 == bv) pk = (a0 << 8) | (0 << 6) | lane;
      if (v1 == bv) pk = min(pk, (a1 << 8) | (1 << 6) | lane);
      if (v2 == bv) pk = min(pk, (a2 << 8) | (2 << 6) | lane);
      if (v3 == bv) pk = min(pk, (a3 << 8) | (3 << 6) | lane);
      int pmin = wave_min_pos_i32(pk);
      int slot = pmin & 0xFF;            // storage index of winning chunk
      cx = CXv[slot]; cy = CYv[slot]; cz = CZv[slot];
    }
    __syncthreads();   // argmax reads vs next-iter writes
  }
#undef FPS_CHUNK_BODY
#undef FPS_CHUNK_REDUCE
}

// -------- ball query: one wave per query, first-32 ascending indices --------
__global__ __launch_bounds__(256) void ball_query_kernel(const float* __restrict__ xyz,
                                                         const float* __restrict__ new_xyz,
                                                         int* __restrict__ idx) {
  const int q = (int)((blockIdx.x * 256 + threadIdx.x) >> 6);
  const int lane = threadIdx.x & 63;
  const int b = q >> 12;
  const float* P = xyz + (size_t)b * kN * 3;
  const float qx = new_xyz[q * 3 + 0];
  const float qy = new_xyz[q * 3 + 1];
  const float qz = new_xyz[q * 3 + 2];
  int cnt = 0;
  int first = -1;
  const int base = q * kNS;
  for (int j = 0; j < kN / 64; j++) {
    const int p = (j << 6) + lane;
    float dx = P[p * 3 + 0] - qx;
    float dy = P[p * 3 + 1] - qy;
    float dz = P[p * 3 + 2] - qz;
    float d = __fadd_rn(__fadd_rn(__fmul_rn(dx, dx), __fmul_rn(dy, dy)),
                        __fmul_rn(dz, dz));
    bool inb = d < 0.25f;
    unsigned long long m = __ballot(inb);
    if (first < 0 && m != 0ull) first = (j << 6) + (__ffsll(m) - 1);
    if (inb && cnt < kNS) {
      int r = cnt + (int)__popcll(m & ((1ull << lane) - 1ull));
      if (r < kNS) idx[base + r] = p;
    }
    cnt += (int)__popcll(m);
    if (cnt >= kNS) break;
  }
  if (cnt < kNS) {
    int fill = (first >= 0) ? first : 0;
    if (lane >= cnt && lane < kNS) idx[base + lane] = fill;
  }
}

// -------- gather + MLP(67->64->64->128) + maxpool + agg(128->128) + score ----
__global__ __launch_bounds__(128) void group_mlp_kernel(
    const float* __restrict__ xyz, const float* __restrict__ new_xyz,
    const float* __restrict__ featsT, const int* __restrict__ nidx,
    const float* __restrict__ w1, const float* __restrict__ b1,
    const float* __restrict__ w2, const float* __restrict__ b2,
    const float* __restrict__ w3, const float* __restrict__ b3,
    const float* __restrict__ wa, const float* __restrict__ ba,
    const float* __restrict__ wc, const float* __restrict__ bc,
    float* __restrict__ aggT, float* __restrict__ scores) {
  __shared__ float smem[2 * 4384];
  const int wid = threadIdx.x >> 6;
  const int lane = threadIdx.x & 63;
  const int q = blockIdx.x * 2 + wid;
  const int b = q >> 12;
  float* Xs = smem + wid * 4384;   // [32][68] input; later reused as H2 [32][64]
  float* H1 = Xs + 32 * 68;        // [32][64]
  float* pool = H1 + 32 * 64;      // [128]
  int* idxs = (int*)(pool + 128);  // [32]

  if (lane < 32) idxs[lane] = nidx[q * kNS + lane];
  const float qx = new_xyz[q * 3 + 0];
  const float qy = new_xyz[q * 3 + 1];
  const float qz = new_xyz[q * 3 + 2];
  __syncthreads();

  const float* P = xyz + (size_t)b * kN * 3;
  const float* F = featsT + (size_t)b * kN * kC;
  if (lane < 32) {
    int p = idxs[lane];
    Xs[lane * 68 + 0] = P[p * 3 + 0] - qx;
    Xs[lane * 68 + 1] = P[p * 3 + 1] - qy;
    Xs[lane * 68 + 2] = P[p * 3 + 2] - qz;
  } else {
    Xs[(lane - 32) * 68 + 67] = 0.0f;   // pad column
  }
  for (int j = 0; j < 32; j++) {
    Xs[j * 68 + 3 + lane] = F[(size_t)idxs[j] * kC + lane];
  }
  __syncthreads();

  float w[68];
  // ---- layer 1: 67 -> 64, lane = out channel ----
  {
    const int o = lane;
#pragma unroll
    for (int k = 0; k < 67; k++) w[k] = w1[o * 67 + k];
    w[67] = 0.0f;
    const float bias = b1[o];
    for (int r = 0; r < 32; r++) {
      float acc = bias;
#pragma unroll
      for (int k4 = 0; k4 < 17; k4++) {
        float4 x = *(const float4*)&Xs[r * 68 + k4 * 4];
        acc += x.x * w[k4 * 4 + 0] + x.y * w[k4 * 4 + 1] +
               x.z * w[k4 * 4 + 2] + x.w * w[k4 * 4 + 3];
      }
      H1[r * 64 + o] = fmaxf(acc, 0.0f);
    }
  }
  __syncthreads();
  // ---- layer 2: 64 -> 64, write H2 into Xs region ----
  {
    const int o = lane;
#pragma unroll
    for (int k = 0; k < 64; k++) w[k] = w2[o * 64 + k];
    const float bias = b2[o];
    for (int r = 0; r < 32; r++) {
      float acc = bias;
#pragma unroll
      for (int k4 = 0; k4 < 16; k4++) {
        float4 x = *(const float4*)&H1[r * 64 + k4 * 4];
        acc += x.x * w[k4 * 4 + 0] + x.y * w[k4 * 4 + 1] +
               x.z * w[k4 * 4 + 2] + x.w * w[k4 * 4 + 3];
      }
      Xs[r * 64 + o] = fmaxf(acc, 0.0f);
    }
  }
  __syncthreads();
  // ---- layer 3: 64 -> 128 (2 out channels per lane) + maxpool over rows ----
  {
    const int c = lane;
    float wB[64];
#pragma unroll
    for (int k = 0; k < 64; k++) {
      w[k] = w3[c * 64 + k];
      wB[k] = w3[(c + 64) * 64 + k];
    }
    const float biasA = b3[c];
    const float biasB = b3[c + 64];
    float pa = 0.0f, pb = 0.0f;   // relu folded: max over relu(h) == max(0, max h)
    for (int r = 0; r < 32; r++) {
      float a = biasA, bb = biasB;
#pragma unroll
      for (int k4 = 0; k4 < 16; k4++) {
        float4 x = *(const float4*)&Xs[r * 64 + k4 * 4];
        a  += x.x * w[k4 * 4 + 0] + x.y * w[k4 * 4 + 1] +
              x.z * w[k4 * 4 + 2] + x.w * w[k4 * 4 + 3];
        bb += x.x * wB[k4 * 4 + 0] + x.y * wB[k4 * 4 + 1] +
              x.z * wB[k4 * 4 + 2] + x.w * wB[k4 * 4 + 3];
      }
      pa = fmaxf(pa, a);
      pb = fmaxf(pb, bb);
    }
    pool[c] = pa;
    pool[c + 64] = pb;
  }
  __syncthreads();
  // ---- aggregation 128->128 + relu, confidence 128->1 ----
  {
    const int c = lane;
    float accA = ba[c], accB = ba[c + 64];
#pragma unroll
    for (int k4 = 0; k4 < 32; k4++) {
      float4 pv = *(const float4*)&pool[k4 * 4];
      float4 wva = *(const float4*)&wa[c * 128 + k4 * 4];
      float4 wvb = *(const float4*)&wa[(c + 64) * 128 + k4 * 4];
      accA += pv.x * wva.x + pv.y * wva.y + pv.z * wva.z + pv.w * wva.w;
      accB += pv.x * wvb.x + pv.y * wvb.y + pv.z * wvb.z + pv.w * wvb.w;
    }
    float aggA = fmaxf(accA, 0.0f);
    float aggB = fmaxf(accB, 0.0f);
    aggT[(size_t)q * 128 + c] = aggA;
    aggT[(size_t)q * 128 + 64 + c] = aggB;
    float partial = aggA * wc[c] + aggB * wc[c + 64];
#pragma unroll
    for (int off = 32; off >= 1; off >>= 1) partial += __shfl_xor(partial, off, 64);
    if (lane == 0) scores[q] = partial + bc[0];
  }
}

extern "C" void kernel_launch(void* const* d_in, const int* in_sizes, int n_in,
                              void* d_out, int out_size, void* d_ws, size_t ws_size,
                              hipStream_t stream) {
  const float* xyz   = (const float*)d_in[0];
  const float* feats = (const float*)d_in[1];
  const float* w1 = (const float*)d_in[2];
  const float* b1 = (const float*)d_in[3];
  const float* w2 = (const float*)d_in[4];
  const float* b2 = (const float*)d_in[5];
  const float* w3 = (const float*)d_in[6];
  const float* b3 = (const float*)d_in[7];
  const float* wa = (const float*)d_in[8];
  const float* ba = (const float*)d_in[9];
  const float* wc = (const float*)d_in[10];
  const float* bc = (const float*)d_in[11];

  float* out_new_xyz = (float*)d_out;                               // B*S*3
  float* out_feat    = out_new_xyz + (size_t)kB * kS * 3;           // B*128*S
  float* out_scores  = out_feat + (size_t)kB * 128 * kS;            // B*S

  // ws layout: featsT [0,8MiB), idx [8MiB,9MiB), aggT [9MiB,13MiB).
  // FPS-prep buffers ALIAS the aggT region (consumed before group_mlp writes).
  char* ws = (char*)d_ws;
  float* featsT = (float*)ws;
  int*   idxbuf = (int*)(ws + (size_t)8 * 1024 * 1024);
  float* aggT   = (float*)(ws + (size_t)9 * 1024 * 1024);
  float* xsb = (float*)(ws + (size_t)9 * 1024 * 1024);               // 2*64KB
  float* ysb = (float*)(ws + (size_t)9 * 1024 * 1024 + 128 * 1024);
  float* zsb = (float*)(ws + (size_t)9 * 1024 * 1024 + 256 * 1024);
  int*   ogb = (int*)  (ws + (size_t)9 * 1024 * 1024 + 384 * 1024);  // 2*64KB
  float* ctrb = (float*)(ws + (size_t)9 * 1024 * 1024 + 512 * 1024); // 6KB
  float* radb = (float*)(ws + (size_t)9 * 1024 * 1024 + 544 * 1024); // 2KB

  transpose_kernel<<<dim3(kN / 32, kC / 32, kB), dim3(32, 8, 1), 0, stream>>>(
      feats, featsT, kC, kN);
  fps_prep_kernel<<<dim3(kB), dim3(1024), 0, stream>>>(
      xyz, xsb, ysb, zsb, ogb, ctrb, radb);
  fps_kernel<<<dim3(kB), dim3(1024), 0, stream>>>(
      xyz, xsb, ysb, zsb, ogb, ctrb, radb, out_new_xyz);
  ball_query_kernel<<<dim3(kB * kS / 4), dim3(256), 0, stream>>>(
      xyz, out_new_xyz, idxbuf);
  group_mlp_kernel<<<dim3(kB * kS / 2), dim3(128), 0, stream>>>(
      xyz, out_new_xyz, featsT, idxbuf,
      w1, b1, w2, b2, w3, b3, wa, ba, wc, bc, aggT, out_scores);
  transpose_kernel<<<dim3(128 / 32, kS / 32, kB), dim3(32, 8, 1), 0, stream>>>(
      aggT, out_feat, kS, 128);
}

// Round 8
// 6389.452 us; speedup vs baseline: 1.8617x; 1.4433x over previous
//
#include <hip/hip_runtime.h>
#include <cstddef>

constexpr int kB = 2;
constexpr int kN = 16384;
constexpr int kC = 64;
constexpr int kS = 4096;    // NPOINT
constexpr int kNS = 32;     // NSAMPLE
constexpr int kNC16 = 1024; // 16-point chunks per batch

__device__ __forceinline__ unsigned expand10(unsigned v) {
  v &= 1023u;
  v = (v | (v << 16)) & 0x030000FFu;
  v = (v | (v <<  8)) & 0x0300F00Fu;
  v = (v | (v <<  4)) & 0x030C30C3u;
  v = (v | (v <<  2)) & 0x09249249u;
  return v;
}

template <int C>
__device__ __forceinline__ unsigned dpp_u32(unsigned x) {
  return (unsigned)__builtin_amdgcn_update_dpp((int)x, (int)x, C, 0xF, 0xF, false);
}
// max over each 16-lane row; valid in ALL lanes (rotations stay in-row)
__device__ __forceinline__ unsigned rowmax16(unsigned x) {
  x = max(x, dpp_u32<0x121>(x));  // row_ror:1
  x = max(x, dpp_u32<0x122>(x));  // row_ror:2
  x = max(x, dpp_u32<0x124>(x));  // row_ror:4
  x = max(x, dpp_u32<0x128>(x));  // row_ror:8
  return x;
}
// one u64-max DPP step on an (hi,lo) pair
template <int C>
__device__ __forceinline__ void u64max_dpp(unsigned& hi, unsigned& lo) {
  unsigned h2 = dpp_u32<C>(hi), l2 = dpp_u32<C>(lo);
  bool g = (h2 > hi) || (h2 == hi && l2 > lo);
  hi = g ? h2 : hi;
  lo = g ? l2 : lo;
}

// -------- transpose [b][Cdim][Ndim] -> [b][Ndim][Cdim], 32x32 tiles --------
__global__ void transpose_kernel(const float* __restrict__ in,
                                 float* __restrict__ out,
                                 int Cdim, int Ndim) {
  __shared__ float tile[32][33];
  int b = blockIdx.z;
  int n0 = blockIdx.x * 32;
  int c0 = blockIdx.y * 32;
  int tx = threadIdx.x;
  const float* inb = in + (size_t)b * Cdim * Ndim;
  float* outb = out + (size_t)b * Cdim * Ndim;
#pragma unroll
  for (int i = threadIdx.y; i < 32; i += 8)
    tile[i][tx] = inb[(size_t)(c0 + i) * Ndim + (n0 + tx)];
  __syncthreads();
#pragma unroll
  for (int i = threadIdx.y; i < 32; i += 8)
    outb[(size_t)(n0 + i) * Cdim + (c0 + tx)] = tile[tx][i];
}

// -------- FPS prep: bbox -> morton -> in-LDS bitonic sort -> packed SoA +
// 16-pt chunk metadata. Sort/meta quality only affects SPEED, never
// correctness (any bijection + conservative radii is exact).
__global__ __launch_bounds__(1024) void fps_prep_kernel(
    const float* __restrict__ xyz, float4* __restrict__ pxyz,
    float* __restrict__ ctr, float* __restrict__ rad) {
  const int b = blockIdx.x;
  const int t = threadIdx.x;
  const int lane = t & 63;
  const int w = t >> 6;
  const float* P = xyz + (size_t)b * kN * 3;
  __shared__ unsigned long long keys[kN];   // 128 KB
  __shared__ float sbb[6][16];

  float mnx = 3e38f, mny = 3e38f, mnz = 3e38f;
  float mxx = -3e38f, mxy = -3e38f, mxz = -3e38f;
  for (int p = t; p < kN; p += 1024) {
    float x = P[p * 3], y = P[p * 3 + 1], z = P[p * 3 + 2];
    mnx = fminf(mnx, x); mny = fminf(mny, y); mnz = fminf(mnz, z);
    mxx = fmaxf(mxx, x); mxy = fmaxf(mxy, y); mxz = fmaxf(mxz, z);
  }
#pragma unroll
  for (int off = 32; off >= 1; off >>= 1) {
    mnx = fminf(mnx, __shfl_xor(mnx, off, 64));
    mny = fminf(mny, __shfl_xor(mny, off, 64));
    mnz = fminf(mnz, __shfl_xor(mnz, off, 64));
    mxx = fmaxf(mxx, __shfl_xor(mxx, off, 64));
    mxy = fmaxf(mxy, __shfl_xor(mxy, off, 64));
    mxz = fmaxf(mxz, __shfl_xor(mxz, off, 64));
  }
  if (lane == 0) {
    sbb[0][w] = mnx; sbb[1][w] = mny; sbb[2][w] = mnz;
    sbb[3][w] = mxx; sbb[4][w] = mxy; sbb[5][w] = mxz;
  }
  __syncthreads();
  mnx = sbb[0][lane & 15]; mny = sbb[1][lane & 15]; mnz = sbb[2][lane & 15];
  mxx = sbb[3][lane & 15]; mxy = sbb[4][lane & 15]; mxz = sbb[5][lane & 15];
#pragma unroll
  for (int off = 8; off >= 1; off >>= 1) {
    mnx = fminf(mnx, __shfl_xor(mnx, off, 64));
    mny = fminf(mny, __shfl_xor(mny, off, 64));
    mnz = fminf(mnz, __shfl_xor(mnz, off, 64));
    mxx = fmaxf(mxx, __shfl_xor(mxx, off, 64));
    mxy = fmaxf(mxy, __shfl_xor(mxy, off, 64));
    mxz = fmaxf(mxz, __shfl_xor(mxz, off, 64));
  }
  __syncthreads();
  const float sx = 1023.0f / fmaxf(mxx - mnx, 1e-20f);
  const float sy = 1023.0f / fmaxf(mxy - mny, 1e-20f);
  const float sz = 1023.0f / fmaxf(mxz - mnz, 1e-20f);
  for (int p = t; p < kN; p += 1024) {
    float x = P[p * 3], y = P[p * 3 + 1], z = P[p * 3 + 2];
    int qx = (int)((x - mnx) * sx); qx = max(0, min(1023, qx));
    int qy = (int)((y - mny) * sy); qy = max(0, min(1023, qy));
    int qz = (int)((z - mnz) * sz); qz = max(0, min(1023, qz));
    unsigned mort = (expand10((unsigned)qx) << 2) |
                    (expand10((unsigned)qy) << 1) | expand10((unsigned)qz);
    keys[p] = ((unsigned long long)mort << 14) | (unsigned)p;
  }
  __syncthreads();
  for (unsigned k = 2; k <= (unsigned)kN; k <<= 1) {
    for (unsigned j = k >> 1; j > 0; j >>= 1) {
      for (int i = t; i < kN; i += 1024) {
        int l = i ^ (int)j;
        if (l > i) {
          unsigned long long a = keys[i], c = keys[l];
          bool asc = ((i & (int)k) == 0);
          if ((a > c) == asc) { keys[i] = c; keys[l] = a; }
        }
      }
      __syncthreads();
    }
  }
  // packed SoA: {x, y, z, orig(int bits)}
  float4* PX = pxyz + (size_t)b * kN;
  for (int i = t; i < kN; i += 1024) {
    int o = (int)(keys[i] & 0x3FFFull);
    PX[i] = float4{P[o * 3], P[o * 3 + 1], P[o * 3 + 2], __int_as_float(o)};
  }
  // 16-point chunk metadata (bounding sphere, conservatively inflated)
  if (t < kNC16) {
    float amn = 3e38f, bmn = 3e38f, cmn = 3e38f;
    float amx = -3e38f, bmx = -3e38f, cmx = -3e38f;
    for (int kk = 0; kk < 16; kk++) {
      int o = (int)(keys[t * 16 + kk] & 0x3FFFull);
      float x = P[o * 3], y = P[o * 3 + 1], z = P[o * 3 + 2];
      amn = fminf(amn, x); amx = fmaxf(amx, x);
      bmn = fminf(bmn, y); bmx = fmaxf(bmx, y);
      cmn = fminf(cmn, z); cmx = fmaxf(cmx, z);
    }
    float ux = (amn + amx) * 0.5f, uy = (bmn + bmx) * 0.5f, uz = (cmn + cmx) * 0.5f;
    float hx = (amx - amn) * 0.5f, hy = (bmx - bmn) * 0.5f, hz = (cmx - cmn) * 0.5f;
    float r = sqrtf(hx * hx + hy * hy + hz * hz) * 1.0002f + 1e-6f;
    ctr[((size_t)b * kNC16 + t) * 3 + 0] = ux;
    ctr[((size_t)b * kNC16 + t) * 3 + 1] = uy;
    ctr[((size_t)b * kNC16 + t) * 3 + 2] = uz;
    rad[(size_t)b * kNC16 + t] = r;
  }
}

// -------- farthest point sampling v8: 16-pt chunks, row-DPP, u64 keys ------
// Chunk c (0..1023) owned by wave w=c&15 at slot s=(c&15)*64+(c>>4); lane l
// of wave w prune-tests chunk (l<<4)|w. Failing chunks processed 4 per pass
// (one per 16-lane row): dist update (exact numpy RNE) + 4-step row_ror DPP
// max + tie row-max over (16383-orig). Per-chunk result = sortable key
// {fbits(maxdist), 16383-minorig}: max key == numpy first-max. Argmax:
// per-wave 6-step DPP u64 max -> LDS[2][16] (dbuf, parity=it&1) -> barrier
// -> 16-entry row reduce; winner coords via one broadcast L2 load.
// ONE barrier per iteration. Skipped chunks provably unchanged (R6 bound).
__global__ __launch_bounds__(1024) void fps_kernel(
    const float* __restrict__ xyz, const float4* __restrict__ pxyz,
    const float* __restrict__ ctr, const float* __restrict__ rad,
    float* __restrict__ new_xyz) {
  const int b = blockIdx.x;
  const int t = threadIdx.x;
  const int lane = t & 63;
  const int w = t >> 6;
  const int g = lane >> 4;          // row within wave
  const int sub = lane & 15;        // lane within row
  const int poff = (w << 4) | sub;  // point offset: p = chunkLane*256 + poff
  const int s0 = (w << 6) | lane;   // slot this lane owns/prunes
  const float* P = xyz + (size_t)b * kN * 3;
  const float4* PX = pxyz + (size_t)b * kN;

  __shared__ float dist[kN];                 // 64 KB
  __shared__ unsigned Mhi[kNC16], Mlo[kNC16];// 8 KB  (key = {fbits, 16383-orig})
  __shared__ float cux[kNC16], cuy[kNC16], cuz[kNC16], crd[kNC16]; // 16 KB
  __shared__ unsigned whi[2][16], wlo[2][16];

  for (int i = t; i < kN; i += 1024) dist[i] = 1e10f;
  if (t < kNC16) {
    const int c = t;
    const int s = ((c & 15) << 6) | (c >> 4);
    cux[s] = ctr[((size_t)b * kNC16 + c) * 3 + 0];
    cuy[s] = ctr[((size_t)b * kNC16 + c) * 3 + 1];
    cuz[s] = ctr[((size_t)b * kNC16 + c) * 3 + 2];
    crd[s] = rad[(size_t)b * kNC16 + c];
    Mhi[s] = __float_as_uint(1e10f);
    Mlo[s] = 16383u;
  }
  __syncthreads();

  float cx = P[0], cy = P[1], cz = P[2];

  for (int it = 0; it < kS; ++it) {
    if (t == 0) {
      float* o = new_xyz + ((size_t)b * kS + it) * 3;
      o[0] = cx; o[1] = cy; o[2] = cz;
    }
    // ---- prune: this lane's chunk; skip is provably exact (R6 bound) ----
    {
      float dxu = cx - cux[s0], dyu = cy - cuy[s0], dzu = cz - cuz[s0];
      float du = sqrtf(dxu * dxu + dyu * dyu + dzu * dzu);
      float lb = du - crd[s0] - 1e-5f;
      float Mv = __uint_as_float(Mhi[s0]);
      bool fail = !((lb > 0.0f) && (lb * lb >= Mv * 1.00001f));
      unsigned long long fmask = __ballot(fail);
      // ---- process failing chunks, 4 per pass (rows may replicate) ----
      while (fmask) {
        int b0 = (int)__ffsll(fmask) - 1; fmask &= fmask - 1;
        int b1 = fmask ? (int)__ffsll(fmask) - 1 : b0; if (fmask) fmask &= fmask - 1;
        int b2 = fmask ? (int)__ffsll(fmask) - 1 : b0; if (fmask) fmask &= fmask - 1;
        int b3 = fmask ? (int)__ffsll(fmask) - 1 : b0; if (fmask) fmask &= fmask - 1;
        int bA = (g & 1) ? b1 : b0;
        int bBq = (g & 1) ? b3 : b2;
        int bg = (g & 2) ? bBq : bA;     // this row's chunk-lane id
        int p = (bg << 8) | poff;        // chunk (bg<<4)|w, point sub
        float4 v = PX[p];
        float dold = dist[p];
        float ddx = cx - v.x, ddy = cy - v.y, ddz = cz - v.z;
        float d = __fadd_rn(__fadd_rn(__fmul_rn(ddx, ddx), __fmul_rn(ddy, ddy)),
                            __fmul_rn(ddz, ddz));
        float dk = fminf(dold, d);
        dist[p] = dk;
        unsigned fb = __float_as_uint(dk);          // monotone on dk >= 0
        unsigned mx = rowmax16(fb);                 // all row lanes valid
        unsigned sel = (fb == mx) ? (16383u - (unsigned)__float_as_int(v.w)) : 0u;
        unsigned m2 = rowmax16(sel);                // -> 16383 - min orig
        if (sub == 0) {
          int sl = (w << 6) | bg;
          Mhi[sl] = mx;
          Mlo[sl] = m2;
        }
      }
    }
    // ---- phase 2a: per-wave u64 key max over own 64 slots (lane63) ----
    {
      unsigned hi = Mhi[s0], lo = Mlo[s0];
      u64max_dpp<0xB1>(hi, lo);    // xor1
      u64max_dpp<0x4E>(hi, lo);    // xor2
      u64max_dpp<0x124>(hi, lo);   // row_ror:4
      u64max_dpp<0x128>(hi, lo);   // row_ror:8  (row max, all lanes)
      u64max_dpp<0x142>(hi, lo);   // row_bcast:15
      u64max_dpp<0x143>(hi, lo);   // row_bcast:31 -> lane 63 valid
      if (lane == 63) { whi[it & 1][w] = hi; wlo[it & 1][w] = lo; }
    }
    __syncthreads();
    // ---- phase 2b: global max over 16 wave keys; coords via one L2 load --
    {
      unsigned hi = whi[it & 1][sub], lo = wlo[it & 1][sub];
      u64max_dpp<0x121>(hi, lo);
      u64max_dpp<0x122>(hi, lo);
      u64max_dpp<0x124>(hi, lo);
      u64max_dpp<0x128>(hi, lo);   // all lanes hold global max key
      int orig = 16383 - (int)(lo & 0x3FFFu);
      cx = P[orig * 3];            // same addr across lanes -> broadcast
      cy = P[orig * 3 + 1];
      cz = P[orig * 3 + 2];
    }
  }
}

// -------- ball query: one wave per query, first-32 ascending indices --------
__global__ __launch_bounds__(256) void ball_query_kernel(const float* __restrict__ xyz,
                                                         const float* __restrict__ new_xyz,
                                                         int* __restrict__ idx) {
  const int q = (int)((blockIdx.x * 256 + threadIdx.x) >> 6);
  const int lane = threadIdx.x & 63;
  const int b = q >> 12;
  const float* P = xyz + (size_t)b * kN * 3;
  const float qx = new_xyz[q * 3 + 0];
  const float qy = new_xyz[q * 3 + 1];
  const float qz = new_xyz[q * 3 + 2];
  int cnt = 0;
  int first = -1;
  const int base = q * kNS;
  for (int j = 0; j < kN / 64; j++) {
    const int p = (j << 6) + lane;
    float dx = P[p * 3 + 0] - qx;
    float dy = P[p * 3 + 1] - qy;
    float dz = P[p * 3 + 2] - qz;
    float d = __fadd_rn(__fadd_rn(__fmul_rn(dx, dx), __fmul_rn(dy, dy)),
                        __fmul_rn(dz, dz));
    bool inb = d < 0.25f;
    unsigned long long m = __ballot(inb);
    if (first < 0 && m != 0ull) first = (j << 6) + (__ffsll(m) - 1);
    if (inb && cnt < kNS) {
      int r = cnt + (int)__popcll(m & ((1ull << lane) - 1ull));
      if (r < kNS) idx[base + r] = p;
    }
    cnt += (int)__popcll(m);
    if (cnt >= kNS) break;
  }
  if (cnt < kNS) {
    int fill = (first >= 0) ? first : 0;
    if (lane >= cnt && lane < kNS) idx[base + lane] = fill;
  }
}

// -------- gather + MLP(67->64->64->128) + maxpool + agg(128->128) + score ----
__global__ __launch_bounds__(128) void group_mlp_kernel(
    const float* __restrict__ xyz, const float* __restrict__ new_xyz,
    const float* __restrict__ featsT, const int* __restrict__ nidx,
    const float* __restrict__ w1, const float* __restrict__ b1,
    const float* __restrict__ w2, const float* __restrict__ b2,
    const float* __restrict__ w3, const float* __restrict__ b3,
    const float* __restrict__ wa, const float* __restrict__ ba,
    const float* __restrict__ wc, const float* __restrict__ bc,
    float* __restrict__ aggT, float* __restrict__ scores) {
  __shared__ float smem[2 * 4384];
  const int wid = threadIdx.x >> 6;
  const int lane = threadIdx.x & 63;
  const int q = blockIdx.x * 2 + wid;
  const int b = q >> 12;
  float* Xs = smem + wid * 4384;   // [32][68] input; later reused as H2 [32][64]
  float* H1 = Xs + 32 * 68;        // [32][64]
  float* pool = H1 + 32 * 64;      // [128]
  int* idxs = (int*)(pool + 128);  // [32]

  if (lane < 32) idxs[lane] = nidx[q * kNS + lane];
  const float qx = new_xyz[q * 3 + 0];
  const float qy = new_xyz[q * 3 + 1];
  const float qz = new_xyz[q * 3 + 2];
  __syncthreads();

  const float* P = xyz + (size_t)b * kN * 3;
  const float* F = featsT + (size_t)b * kN * kC;
  if (lane < 32) {
    int p = idxs[lane];
    Xs[lane * 68 + 0] = P[p * 3 + 0] - qx;
    Xs[lane * 68 + 1] = P[p * 3 + 1] - qy;
    Xs[lane * 68 + 2] = P[p * 3 + 2] - qz;
  } else {
    Xs[(lane - 32) * 68 + 67] = 0.0f;   // pad column
  }
  for (int j = 0; j < 32; j++) {
    Xs[j * 68 + 3 + lane] = F[(size_t)idxs[j] * kC + lane];
  }
  __syncthreads();

  float w[68];
  // ---- layer 1: 67 -> 64, lane = out channel ----
  {
    const int o = lane;
#pragma unroll
    for (int k = 0; k < 67; k++) w[k] = w1[o * 67 + k];
    w[67] = 0.0f;
    const float bias = b1[o];
    for (int r = 0; r < 32; r++) {
      float acc = bias;
#pragma unroll
      for (int k4 = 0; k4 < 17; k4++) {
        float4 x = *(const float4*)&Xs[r * 68 + k4 * 4];
        acc += x.x * w[k4 * 4 + 0] + x.y * w[k4 * 4 + 1] +
               x.z * w[k4 * 4 + 2] + x.w * w[k4 * 4 + 3];
      }
      H1[r * 64 + o] = fmaxf(acc, 0.0f);
    }
  }
  __syncthreads();
  // ---- layer 2: 64 -> 64, write H2 into Xs region ----
  {
    const int o = lane;
#pragma unroll
    for (int k = 0; k < 64; k++) w[k] = w2[o * 64 + k];
    const float bias = b2[o];
    for (int r = 0; r < 32; r++) {
      float acc = bias;
#pragma unroll
      for (int k4 = 0; k4 < 16; k4++) {
        float4 x = *(const float4*)&H1[r * 64 + k4 * 4];
        acc += x.x * w[k4 * 4 + 0] + x.y * w[k4 * 4 + 1] +
               x.z * w[k4 * 4 + 2] + x.w * w[k4 * 4 + 3];
      }
      Xs[r * 64 + o] = fmaxf(acc, 0.0f);
    }
  }
  __syncthreads();
  // ---- layer 3: 64 -> 128 (2 out channels per lane) + maxpool over rows ----
  {
    const int c = lane;
    float wB[64];
#pragma unroll
    for (int k = 0; k < 64; k++) {
      w[k] = w3[c * 64 + k];
      wB[k] = w3[(c + 64) * 64 + k];
    }
    const float biasA = b3[c];
    const float biasB = b3[c + 64];
    float pa = 0.0f, pb = 0.0f;   // relu folded: max over relu(h) == max(0, max h)
    for (int r = 0; r < 32; r++) {
      float a = biasA, bb = biasB;
#pragma unroll
      for (int k4 = 0; k4 < 16; k4++) {
        float4 x = *(const float4*)&Xs[r * 64 + k4 * 4];
        a  += x.x * w[k4 * 4 + 0] + x.y * w[k4 * 4 + 1] +
              x.z * w[k4 * 4 + 2] + x.w * w[k4 * 4 + 3];
        bb += x.x * wB[k4 * 4 + 0] + x.y * wB[k4 * 4 + 1] +
              x.z * wB[k4 * 4 + 2] + x.w * wB[k4 * 4 + 3];
      }
      pa = fmaxf(pa, a);
      pb = fmaxf(pb, bb);
    }
    pool[c] = pa;
    pool[c + 64] = pb;
  }
  __syncthreads();
  // ---- aggregation 128->128 + relu, confidence 128->1 ----
  {
    const int c = lane;
    float accA = ba[c], accB = ba[c + 64];
#pragma unroll
    for (int k4 = 0; k4 < 32; k4++) {
      float4 pv = *(const float4*)&pool[k4 * 4];
      float4 wva = *(const float4*)&wa[c * 128 + k4 * 4];
      float4 wvb = *(const float4*)&wa[(c + 64) * 128 + k4 * 4];
      accA += pv.x * wva.x + pv.y * wva.y + pv.z * wva.z + pv.w * wva.w;
      accB += pv.x * wvb.x + pv.y * wvb.y + pv.z * wvb.z + pv.w * wvb.w;
    }
    float aggA = fmaxf(accA, 0.0f);
    float aggB = fmaxf(accB, 0.0f);
    aggT[(size_t)q * 128 + c] = aggA;
    aggT[(size_t)q * 128 + 64 + c] = aggB;
    float partial = aggA * wc[c] + aggB * wc[c + 64];
#pragma unroll
    for (int off = 32; off >= 1; off >>= 1) partial += __shfl_xor(partial, off, 64);
    if (lane == 0) scores[q] = partial + bc[0];
  }
}

extern "C" void kernel_launch(void* const* d_in, const int* in_sizes, int n_in,
                              void* d_out, int out_size, void* d_ws, size_t ws_size,
                              hipStream_t stream) {
  const float* xyz   = (const float*)d_in[0];
  const float* feats = (const float*)d_in[1];
  const float* w1 = (const float*)d_in[2];
  const float* b1 = (const float*)d_in[3];
  const float* w2 = (const float*)d_in[4];
  const float* b2 = (const float*)d_in[5];
  const float* w3 = (const float*)d_in[6];
  const float* b3 = (const float*)d_in[7];
  const float* wa = (const float*)d_in[8];
  const float* ba = (const float*)d_in[9];
  const float* wc = (const float*)d_in[10];
  const float* bc = (const float*)d_in[11];

  float* out_new_xyz = (float*)d_out;                               // B*S*3
  float* out_feat    = out_new_xyz + (size_t)kB * kS * 3;           // B*128*S
  float* out_scores  = out_feat + (size_t)kB * 128 * kS;            // B*S

  // ws layout: featsT [0,8MiB), idx [8MiB,9MiB), aggT [9MiB,13MiB).
  // FPS-prep buffers ALIAS the aggT region (consumed before group_mlp writes):
  // pxyz 512KB, ctr 24KB, rad 8KB.
  char* ws = (char*)d_ws;
  float* featsT = (float*)ws;
  int*   idxbuf = (int*)(ws + (size_t)8 * 1024 * 1024);
  float* aggT   = (float*)(ws + (size_t)9 * 1024 * 1024);
  float4* pxyzb = (float4*)(ws + (size_t)9 * 1024 * 1024);
  float* ctrb   = (float*)(ws + (size_t)9 * 1024 * 1024 + 512 * 1024);
  float* radb   = (float*)(ws + (size_t)9 * 1024 * 1024 + 544 * 1024);

  transpose_kernel<<<dim3(kN / 32, kC / 32, kB), dim3(32, 8, 1), 0, stream>>>(
      feats, featsT, kC, kN);
  fps_prep_kernel<<<dim3(kB), dim3(1024), 0, stream>>>(
      xyz, pxyzb, ctrb, radb);
  fps_kernel<<<dim3(kB), dim3(1024), 0, stream>>>(
      xyz, pxyzb, ctrb, radb, out_new_xyz);
  ball_query_kernel<<<dim3(kB * kS / 4), dim3(256), 0, stream>>>(
      xyz, out_new_xyz, idxbuf);
  group_mlp_kernel<<<dim3(kB * kS / 2), dim3(128), 0, stream>>>(
      xyz, out_new_xyz, featsT, idxbuf,
      w1, b1, w2, b2, w3, b3, wa, ba, wc, bc, aggT, out_scores);
  transpose_kernel<<<dim3(128 / 32, kS / 32, kB), dim3(32, 8, 1), 0, stream>>>(
      aggT, out_feat, kS, 128);
}

// Round 9
// 6175.453 us; speedup vs baseline: 1.9263x; 1.0347x over previous
//
#include <hip/hip_runtime.h>
#include <cstddef>

constexpr int kB = 2;
constexpr int kN = 16384;
constexpr int kC = 64;
constexpr int kS = 4096;    // NPOINT
constexpr int kNS = 32;     // NSAMPLE
constexpr int kNC16 = 1024; // 16-point chunks per batch
constexpr int kNP = kN / 2; // point pairs per batch

typedef float f32x2 __attribute__((ext_vector_type(2)));

__device__ __forceinline__ unsigned expand10(unsigned v) {
  v &= 1023u;
  v = (v | (v << 16)) & 0x030000FFu;
  v = (v | (v <<  8)) & 0x0300F00Fu;
  v = (v | (v <<  4)) & 0x030C30C3u;
  v = (v | (v <<  2)) & 0x09249249u;
  return v;
}

template <int C>
__device__ __forceinline__ unsigned dpp_u32(unsigned x) {
  return (unsigned)__builtin_amdgcn_update_dpp((int)x, (int)x, C, 0xF, 0xF, false);
}
// max over each aligned 8-lane group (quad xor1, xor2, half-row mirror)
__device__ __forceinline__ unsigned max8(unsigned x) {
  x = max(x, dpp_u32<0xB1>(x));   // quad_perm [1,0,3,2]
  x = max(x, dpp_u32<0x4E>(x));   // quad_perm [2,3,0,1]
  x = max(x, dpp_u32<0x141>(x));  // row_half_mirror
  return x;
}
// one u64-max DPP step on an (hi,lo) pair
template <int C>
__device__ __forceinline__ void u64max_dpp(unsigned& hi, unsigned& lo) {
  unsigned h2 = dpp_u32<C>(hi), l2 = dpp_u32<C>(lo);
  bool g = (h2 > hi) || (h2 == hi && l2 > lo);
  hi = g ? h2 : hi;
  lo = g ? l2 : lo;
}

#define PK_ADD(d, a, b) asm("v_pk_add_f32 %0, %1, %2" : "=v"(d) : "v"(a), "v"(b))
#define PK_MUL(d, a, b) asm("v_pk_mul_f32 %0, %1, %2" : "=v"(d) : "v"(a), "v"(b))

// -------- transpose [b][Cdim][Ndim] -> [b][Ndim][Cdim], 32x32 tiles --------
__global__ void transpose_kernel(const float* __restrict__ in,
                                 float* __restrict__ out,
                                 int Cdim, int Ndim) {
  __shared__ float tile[32][33];
  int b = blockIdx.z;
  int n0 = blockIdx.x * 32;
  int c0 = blockIdx.y * 32;
  int tx = threadIdx.x;
  const float* inb = in + (size_t)b * Cdim * Ndim;
  float* outb = out + (size_t)b * Cdim * Ndim;
#pragma unroll
  for (int i = threadIdx.y; i < 32; i += 8)
    tile[i][tx] = inb[(size_t)(c0 + i) * Ndim + (n0 + tx)];
  __syncthreads();
#pragma unroll
  for (int i = threadIdx.y; i < 32; i += 8)
    outb[(size_t)(n0 + i) * Cdim + (c0 + tx)] = tile[tx][i];
}

// -------- FPS prep: bbox -> morton -> in-LDS bitonic sort -> pair-SoA planes
// + 16-pt chunk AABB metadata. Sort/meta quality only affects SPEED, never
// correctness (any bijection + conservative AABB is exact).
__global__ __launch_bounds__(1024) void fps_prep_kernel(
    const float* __restrict__ xyz, float* __restrict__ pxx,
    float* __restrict__ pxy, float* __restrict__ pxz,
    unsigned* __restrict__ pxo, float* __restrict__ aabb) {
  const int b = blockIdx.x;
  const int t = threadIdx.x;
  const int lane = t & 63;
  const int w = t >> 6;
  const float* P = xyz + (size_t)b * kN * 3;
  __shared__ unsigned long long keys[kN];   // 128 KB
  __shared__ float sbb[6][16];

  float mnx = 3e38f, mny = 3e38f, mnz = 3e38f;
  float mxx = -3e38f, mxy = -3e38f, mxz = -3e38f;
  for (int p = t; p < kN; p += 1024) {
    float x = P[p * 3], y = P[p * 3 + 1], z = P[p * 3 + 2];
    mnx = fminf(mnx, x); mny = fminf(mny, y); mnz = fminf(mnz, z);
    mxx = fmaxf(mxx, x); mxy = fmaxf(mxy, y); mxz = fmaxf(mxz, z);
  }
#pragma unroll
  for (int off = 32; off >= 1; off >>= 1) {
    mnx = fminf(mnx, __shfl_xor(mnx, off, 64));
    mny = fminf(mny, __shfl_xor(mny, off, 64));
    mnz = fminf(mnz, __shfl_xor(mnz, off, 64));
    mxx = fmaxf(mxx, __shfl_xor(mxx, off, 64));
    mxy = fmaxf(mxy, __shfl_xor(mxy, off, 64));
    mxz = fmaxf(mxz, __shfl_xor(mxz, off, 64));
  }
  if (lane == 0) {
    sbb[0][w] = mnx; sbb[1][w] = mny; sbb[2][w] = mnz;
    sbb[3][w] = mxx; sbb[4][w] = mxy; sbb[5][w] = mxz;
  }
  __syncthreads();
  mnx = sbb[0][lane & 15]; mny = sbb[1][lane & 15]; mnz = sbb[2][lane & 15];
  mxx = sbb[3][lane & 15]; mxy = sbb[4][lane & 15]; mxz = sbb[5][lane & 15];
#pragma unroll
  for (int off = 8; off >= 1; off >>= 1) {
    mnx = fminf(mnx, __shfl_xor(mnx, off, 64));
    mny = fminf(mny, __shfl_xor(mny, off, 64));
    mnz = fminf(mnz, __shfl_xor(mnz, off, 64));
    mxx = fmaxf(mxx, __shfl_xor(mxx, off, 64));
    mxy = fmaxf(mxy, __shfl_xor(mxy, off, 64));
    mxz = fmaxf(mxz, __shfl_xor(mxz, off, 64));
  }
  __syncthreads();
  const float sx = 1023.0f / fmaxf(mxx - mnx, 1e-20f);
  const float sy = 1023.0f / fmaxf(mxy - mny, 1e-20f);
  const float sz = 1023.0f / fmaxf(mxz - mnz, 1e-20f);
  for (int p = t; p < kN; p += 1024) {
    float x = P[p * 3], y = P[p * 3 + 1], z = P[p * 3 + 2];
    int qx = (int)((x - mnx) * sx); qx = max(0, min(1023, qx));
    int qy = (int)((y - mny) * sy); qy = max(0, min(1023, qy));
    int qz = (int)((z - mnz) * sz); qz = max(0, min(1023, qz));
    unsigned mort = (expand10((unsigned)qx) << 2) |
                    (expand10((unsigned)qy) << 1) | expand10((unsigned)qz);
    keys[p] = ((unsigned long long)mort << 14) | (unsigned)p;
  }
  __syncthreads();
  for (unsigned k = 2; k <= (unsigned)kN; k <<= 1) {
    for (unsigned j = k >> 1; j > 0; j >>= 1) {
      for (int i = t; i < kN; i += 1024) {
        int l = i ^ (int)j;
        if (l > i) {
          unsigned long long a = keys[i], c = keys[l];
          bool asc = ((i & (int)k) == 0);
          if ((a > c) == asc) { keys[i] = c; keys[l] = a; }
        }
      }
      __syncthreads();
    }
  }
  // pair-SoA planes: pair j of chunk c holds sorted points c*16+j (.x half)
  // and c*16+j+8 (.y half). Float index = c*16 + (j&7)*2 + (j>>3).
  float* FX = pxx + (size_t)b * kN;
  float* FY = pxy + (size_t)b * kN;
  float* FZ = pxz + (size_t)b * kN;
  unsigned* FO = pxo + (size_t)b * kN;
  for (int i = t; i < kN; i += 1024) {
    int o = (int)(keys[i] & 0x3FFFull);
    int c = i >> 4, j = i & 15;
    int fi = c * 16 + ((j & 7) << 1) + (j >> 3);
    FX[fi] = P[o * 3];
    FY[fi] = P[o * 3 + 1];
    FZ[fi] = P[o * 3 + 2];
    FO[fi] = 16383u - (unsigned)o;   // tie key: max(16383-o) == min orig
  }
  // 16-pt chunk AABB: center + inflated half-extents (covers fp rounding)
  if (t < kNC16) {
    float amn = 3e38f, bmn = 3e38f, cmn = 3e38f;
    float amx = -3e38f, bmx = -3e38f, cmx = -3e38f;
    for (int kk = 0; kk < 16; kk++) {
      int o = (int)(keys[t * 16 + kk] & 0x3FFFull);
      float x = P[o * 3], y = P[o * 3 + 1], z = P[o * 3 + 2];
      amn = fminf(amn, x); amx = fmaxf(amx, x);
      bmn = fminf(bmn, y); bmx = fmaxf(bmx, y);
      cmn = fminf(cmn, z); cmx = fmaxf(cmx, z);
    }
    float* AB = aabb + (size_t)b * 6 * kNC16;
    AB[0 * kNC16 + t] = (amn + amx) * 0.5f;
    AB[1 * kNC16 + t] = (bmn + bmx) * 0.5f;
    AB[2 * kNC16 + t] = (cmn + cmx) * 0.5f;
    AB[3 * kNC16 + t] = (amx - amn) * 0.5f * 1.0001f + 2e-7f;
    AB[4 * kNC16 + t] = (bmx - bmn) * 0.5f * 1.0001f + 2e-7f;
    AB[5 * kNC16 + t] = (cmx - cmn) * 0.5f * 1.0001f + 2e-7f;
  }
}

// -------- FPS v9: 16-pt chunks, AABB prune, pack-2 pk math, 8 chunks/pass --
// Wave w owns chunks {(l<<4)|w}; lane l prune-tests its chunk via AABB
// point-to-box bound (meta in registers, asm-pinned). Failing chunks are
// compacted into a per-wave LDS list once per iter; each pass processes 8
// chunks (8 lanes/chunk, 2 pts/lane via v_pk_* — IEEE RNE per half, proven
// R5). Per-chunk result = {fbits(maxdist), max(16383-orig among ties)} ==
// numpy first-max key. Phase 2 (u64-DPP wave max -> LDS dbuf -> barrier ->
// 16-key reduce -> broadcast coord load) unchanged from R8. One barrier/iter.
// Skipped chunks provably unchanged: lb2 >= M*1.00001+1e-5 with inflated
// half-extents over-covers all fp rounding (margin >3x worst-case error).
__global__ __launch_bounds__(1024) void fps_kernel(
    const float* __restrict__ xyz,
    const float* __restrict__ pxx, const float* __restrict__ pxy,
    const float* __restrict__ pxz, const unsigned* __restrict__ pxo,
    const float* __restrict__ aabb, float* __restrict__ new_xyz) {
  const int b = blockIdx.x;
  const int t = threadIdx.x;
  const int lane = t & 63;
  const int w = t >> 6;
  const int grp = lane >> 3;        // 8-lane group id (chunk slot in pass)
  const int sub8 = lane & 7;        // lane within group (pair index)
  const int s0 = (w << 6) | lane;   // M2 slot owned by this lane
  const float* P = xyz + (size_t)b * kN * 3;
  const f32x2* XP = (const f32x2*)(pxx + (size_t)b * kN);
  const f32x2* YP = (const f32x2*)(pxy + (size_t)b * kN);
  const f32x2* ZP = (const f32x2*)(pxz + (size_t)b * kN);
  const uint2* OP = (const uint2*)(pxo + (size_t)b * kN);

  __shared__ f32x2 dpair[kNP];        // 64 KB  min-dist pairs
  __shared__ uint2 M2[kNC16];         // 8 KB   per-chunk key {fb, tieLo}
  __shared__ unsigned list_[16][64];  // 4 KB   per-wave failing-chunk list
  __shared__ unsigned whi[2][16], wlo[2][16];

  for (int i = t; i < kNP; i += 1024) dpair[i] = f32x2{1e10f, 1e10f};
  if (t < kNC16) M2[t] = uint2{__float_as_uint(1e10f), 0u};

  // AABB meta for this lane's chunk -> registers, pinned opaque (R5 trick)
  const int c0 = (lane << 4) | w;
  const float* AB = aabb + (size_t)b * 6 * kNC16;
  float ux = AB[c0], uy = AB[kNC16 + c0], uz = AB[2 * kNC16 + c0];
  float hx = AB[3 * kNC16 + c0], hy = AB[4 * kNC16 + c0], hz = AB[5 * kNC16 + c0];
  asm volatile("" : "+v"(ux), "+v"(uy), "+v"(uz), "+v"(hx), "+v"(hy), "+v"(hz));
  __syncthreads();

  float cx = P[0], cy = P[1], cz = P[2];

  for (int it = 0; it < kS; ++it) {
    if (t == 0) {
      float* o = new_xyz + ((size_t)b * kS + it) * 3;
      o[0] = cx; o[1] = cy; o[2] = cz;
    }
    // ---- AABB prune: lb2 = squared point-to-box distance (conservative) --
    {
      float txd = fmaxf(fabsf(cx - ux) - hx, 0.0f);
      float tyd = fmaxf(fabsf(cy - uy) - hy, 0.0f);
      float tzd = fmaxf(fabsf(cz - uz) - hz, 0.0f);
      float lb2 = txd * txd + tyd * tyd + tzd * tzd;
      float Mv = __uint_as_float(M2[s0].x);
      bool fail = !(lb2 >= Mv * 1.00001f + 1e-5f);
      unsigned long long fmask = __ballot(fail);
      int nf = (int)__popcll(fmask);
      if (fail) {
        int pos = (int)__popcll(fmask & ((1ull << lane) - 1ull));
        list_[w][pos] = (unsigned)lane;
      }
      const f32x2 ncx = f32x2{-cx, -cx};
      const f32x2 ncy = f32x2{-cy, -cy};
      const f32x2 ncz = f32x2{-cz, -cz};
      const int npass = (nf + 7) >> 3;
      for (int i = 0; i < npass; ++i) {
        int idx = min(i * 8 + grp, nf - 1);           // tail replication: benign
        int cl = (int)list_[w][idx];
        int pb = (((cl << 4) | w) << 3) | sub8;
        f32x2 xp = XP[pb], yp = YP[pb], zp = ZP[pb];
        uint2 op = OP[pb];
        f32x2 dold = dpair[pb];
        f32x2 dx_, dy_, dz_, xx_, yy_, zz_, s1_, d2_;
        PK_ADD(dx_, xp, ncx);   // p + (-c) == p - c exactly; square kills sign
        PK_ADD(dy_, yp, ncy);
        PK_ADD(dz_, zp, ncz);
        PK_MUL(xx_, dx_, dx_);
        PK_MUL(yy_, dy_, dy_);
        PK_MUL(zz_, dz_, dz_);
        PK_ADD(s1_, xx_, yy_);
        PK_ADD(d2_, s1_, zz_);
        f32x2 dk;
        dk.x = fminf(dold.x, d2_.x);
        dk.y = fminf(dold.y, d2_.y);
        dpair[pb] = dk;
        unsigned fa = __float_as_uint(dk.x), fbv = __float_as_uint(dk.y);
        unsigned mx = max8(max(fa, fbv));             // bit-max == fmax (>=0)
        unsigned sa = (fa == mx) ? op.x : 0u;
        unsigned sb = (fbv == mx) ? op.y : 0u;
        unsigned m2v = max8(max(sa, sb));             // max(16383-o) == min o
        if (sub8 == 0) M2[(w << 6) | cl] = uint2{mx, m2v};
      }
    }
    // ---- phase 2a: per-wave u64 key max over own 64 slots (lane63) ----
    {
      uint2 m = M2[s0];
      unsigned hi = m.x, lo = m.y;
      u64max_dpp<0xB1>(hi, lo);
      u64max_dpp<0x4E>(hi, lo);
      u64max_dpp<0x124>(hi, lo);   // row_ror:4
      u64max_dpp<0x128>(hi, lo);   // row_ror:8
      u64max_dpp<0x142>(hi, lo);   // row_bcast:15
      u64max_dpp<0x143>(hi, lo);   // row_bcast:31 -> lane 63 valid
      if (lane == 63) { whi[it & 1][w] = hi; wlo[it & 1][w] = lo; }
    }
    __syncthreads();
    // ---- phase 2b: global max over 16 wave keys; coords via L2 broadcast --
    {
      unsigned hi = whi[it & 1][lane & 15], lo = wlo[it & 1][lane & 15];
      u64max_dpp<0x121>(hi, lo);
      u64max_dpp<0x122>(hi, lo);
      u64max_dpp<0x124>(hi, lo);
      u64max_dpp<0x128>(hi, lo);   // all lanes hold global max key
      int orig = 16383 - (int)(lo & 0x3FFFu);
      cx = P[orig * 3];
      cy = P[orig * 3 + 1];
      cz = P[orig * 3 + 2];
    }
  }
}

// -------- ball query: one wave per query, first-32 ascending indices --------
__global__ __launch_bounds__(256) void ball_query_kernel(const float* __restrict__ xyz,
                                                         const float* __restrict__ new_xyz,
                                                         int* __restrict__ idx) {
  const int q = (int)((blockIdx.x * 256 + threadIdx.x) >> 6);
  const int lane = threadIdx.x & 63;
  const int b = q >> 12;
  const float* P = xyz + (size_t)b * kN * 3;
  const float qx = new_xyz[q * 3 + 0];
  const float qy = new_xyz[q * 3 + 1];
  const float qz = new_xyz[q * 3 + 2];
  int cnt = 0;
  int first = -1;
  const int base = q * kNS;
  for (int j = 0; j < kN / 64; j++) {
    const int p = (j << 6) + lane;
    float dx = P[p * 3 + 0] - qx;
    float dy = P[p * 3 + 1] - qy;
    float dz = P[p * 3 + 2] - qz;
    float d = __fadd_rn(__fadd_rn(__fmul_rn(dx, dx), __fmul_rn(dy, dy)),
                        __fmul_rn(dz, dz));
    bool inb = d < 0.25f;
    unsigned long long m = __ballot(inb);
    if (first < 0 && m != 0ull) first = (j << 6) + (__ffsll(m) - 1);
    if (inb && cnt < kNS) {
      int r = cnt + (int)__popcll(m & ((1ull << lane) - 1ull));
      if (r < kNS) idx[base + r] = p;
    }
    cnt += (int)__popcll(m);
    if (cnt >= kNS) break;
  }
  if (cnt < kNS) {
    int fill = (first >= 0) ? first : 0;
    if (lane >= cnt && lane < kNS) idx[base + lane] = fill;
  }
}

// -------- gather + MLP(67->64->64->128) + maxpool + agg(128->128) + score ----
__global__ __launch_bounds__(128) void group_mlp_kernel(
    const float* __restrict__ xyz, const float* __restrict__ new_xyz,
    const float* __restrict__ featsT, const int* __restrict__ nidx,
    const float* __restrict__ w1, const float* __restrict__ b1,
    const float* __restrict__ w2, const float* __restrict__ b2,
    const float* __restrict__ w3, const float* __restrict__ b3,
    const float* __restrict__ wa, const float* __restrict__ ba,
    const float* __restrict__ wc, const float* __restrict__ bc,
    float* __restrict__ aggT, float* __restrict__ scores) {
  __shared__ float smem[2 * 4384];
  const int wid = threadIdx.x >> 6;
  const int lane = threadIdx.x & 63;
  const int q = blockIdx.x * 2 + wid;
  const int b = q >> 12;
  float* Xs = smem + wid * 4384;   // [32][68] input; later reused as H2 [32][64]
  float* H1 = Xs + 32 * 68;        // [32][64]
  float* pool = H1 + 32 * 64;      // [128]
  int* idxs = (int*)(pool + 128);  // [32]

  if (lane < 32) idxs[lane] = nidx[q * kNS + lane];
  const float qx = new_xyz[q * 3 + 0];
  const float qy = new_xyz[q * 3 + 1];
  const float qz = new_xyz[q * 3 + 2];
  __syncthreads();

  const float* P = xyz + (size_t)b * kN * 3;
  const float* F = featsT + (size_t)b * kN * kC;
  if (lane < 32) {
    int p = idxs[lane];
    Xs[lane * 68 + 0] = P[p * 3 + 0] - qx;
    Xs[lane * 68 + 1] = P[p * 3 + 1] - qy;
    Xs[lane * 68 + 2] = P[p * 3 + 2] - qz;
  } else {
    Xs[(lane - 32) * 68 + 67] = 0.0f;   // pad column
  }
  for (int j = 0; j < 32; j++) {
    Xs[j * 68 + 3 + lane] = F[(size_t)idxs[j] * kC + lane];
  }
  __syncthreads();

  float w[68];
  // ---- layer 1: 67 -> 64, lane = out channel ----
  {
    const int o = lane;
#pragma unroll
    for (int k = 0; k < 67; k++) w[k] = w1[o * 67 + k];
    w[67] = 0.0f;
    const float bias = b1[o];
    for (int r = 0; r < 32; r++) {
      float acc = bias;
#pragma unroll
      for (int k4 = 0; k4 < 17; k4++) {
        float4 x = *(const float4*)&Xs[r * 68 + k4 * 4];
        acc += x.x * w[k4 * 4 + 0] + x.y * w[k4 * 4 + 1] +
               x.z * w[k4 * 4 + 2] + x.w * w[k4 * 4 + 3];
      }
      H1[r * 64 + o] = fmaxf(acc, 0.0f);
    }
  }
  __syncthreads();
  // ---- layer 2: 64 -> 64, write H2 into Xs region ----
  {
    const int o = lane;
#pragma unroll
    for (int k = 0; k < 64; k++) w[k] = w2[o * 64 + k];
    const float bias = b2[o];
    for (int r = 0; r < 32; r++) {
      float acc = bias;
#pragma unroll
      for (int k4 = 0; k4 < 16; k4++) {
        float4 x = *(const float4*)&H1[r * 64 + k4 * 4];
        acc += x.x * w[k4 * 4 + 0] + x.y * w[k4 * 4 + 1] +
               x.z * w[k4 * 4 + 2] + x.w * w[k4 * 4 + 3];
      }
      Xs[r * 64 + o] = fmaxf(acc, 0.0f);
    }
  }
  __syncthreads();
  // ---- layer 3: 64 -> 128 (2 out channels per lane) + maxpool over rows ----
  {
    const int c = lane;
    float wB[64];
#pragma unroll
    for (int k = 0; k < 64; k++) {
      w[k] = w3[c * 64 + k];
      wB[k] = w3[(c + 64) * 64 + k];
    }
    const float biasA = b3[c];
    const float biasB = b3[c + 64];
    float pa = 0.0f, pb = 0.0f;   // relu folded: max over relu(h) == max(0, max h)
    for (int r = 0; r < 32; r++) {
      float a = biasA, bb = biasB;
#pragma unroll
      for (int k4 = 0; k4 < 16; k4++) {
        float4 x = *(const float4*)&Xs[r * 64 + k4 * 4];
        a  += x.x * w[k4 * 4 + 0] + x.y * w[k4 * 4 + 1] +
              x.z * w[k4 * 4 + 2] + x.w * w[k4 * 4 + 3];
        bb += x.x * wB[k4 * 4 + 0] + x.y * wB[k4 * 4 + 1] +
              x.z * wB[k4 * 4 + 2] + x.w * wB[k4 * 4 + 3];
      }
      pa = fmaxf(pa, a);
      pb = fmaxf(pb, bb);
    }
    pool[c] = pa;
    pool[c + 64] = pb;
  }
  __syncthreads();
  // ---- aggregation 128->128 + relu, confidence 128->1 ----
  {
    const int c = lane;
    float accA = ba[c], accB = ba[c + 64];
#pragma unroll
    for (int k4 = 0; k4 < 32; k4++) {
      float4 pv = *(const float4*)&pool[k4 * 4];
      float4 wva = *(const float4*)&wa[c * 128 + k4 * 4];
      float4 wvb = *(const float4*)&wa[(c + 64) * 128 + k4 * 4];
      accA += pv.x * wva.x + pv.y * wva.y + pv.z * wva.z + pv.w * wva.w;
      accB += pv.x * wvb.x + pv.y * wvb.y + pv.z * wvb.z + pv.w * wvb.w;
    }
    float aggA = fmaxf(accA, 0.0f);
    float aggB = fmaxf(accB, 0.0f);
    aggT[(size_t)q * 128 + c] = aggA;
    aggT[(size_t)q * 128 + 64 + c] = aggB;
    float partial = aggA * wc[c] + aggB * wc[c + 64];
#pragma unroll
    for (int off = 32; off >= 1; off >>= 1) partial += __shfl_xor(partial, off, 64);
    if (lane == 0) scores[q] = partial + bc[0];
  }
}

extern "C" void kernel_launch(void* const* d_in, const int* in_sizes, int n_in,
                              void* d_out, int out_size, void* d_ws, size_t ws_size,
                              hipStream_t stream) {
  const float* xyz   = (const float*)d_in[0];
  const float* feats = (const float*)d_in[1];
  const float* w1 = (const float*)d_in[2];
  const float* b1 = (const float*)d_in[3];
  const float* w2 = (const float*)d_in[4];
  const float* b2 = (const float*)d_in[5];
  const float* w3 = (const float*)d_in[6];
  const float* b3 = (const float*)d_in[7];
  const float* wa = (const float*)d_in[8];
  const float* ba = (const float*)d_in[9];
  const float* wc = (const float*)d_in[10];
  const float* bc = (const float*)d_in[11];

  float* out_new_xyz = (float*)d_out;                               // B*S*3
  float* out_feat    = out_new_xyz + (size_t)kB * kS * 3;           // B*128*S
  float* out_scores  = out_feat + (size_t)kB * 128 * kS;            // B*S

  // ws layout: featsT [0,8MiB), idx [8MiB,9MiB), aggT [9MiB,13MiB).
  // FPS-prep buffers ALIAS the aggT region (consumed before group_mlp writes):
  // pxx/pxy/pxz/pxo 4x128KB, aabb 48KB.
  char* ws = (char*)d_ws;
  float* featsT = (float*)ws;
  int*   idxbuf = (int*)(ws + (size_t)8 * 1024 * 1024);
  float* aggT   = (float*)(ws + (size_t)9 * 1024 * 1024);
  float*    pxx = (float*)(ws + (size_t)9 * 1024 * 1024);
  float*    pxy = (float*)(ws + (size_t)9 * 1024 * 1024 + 128 * 1024);
  float*    pxz = (float*)(ws + (size_t)9 * 1024 * 1024 + 256 * 1024);
  unsigned* pxo = (unsigned*)(ws + (size_t)9 * 1024 * 1024 + 384 * 1024);
  float*   aabb = (float*)(ws + (size_t)9 * 1024 * 1024 + 512 * 1024);

  transpose_kernel<<<dim3(kN / 32, kC / 32, kB), dim3(32, 8, 1), 0, stream>>>(
      feats, featsT, kC, kN);
  fps_prep_kernel<<<dim3(kB), dim3(1024), 0, stream>>>(
      xyz, pxx, pxy, pxz, pxo, aabb);
  fps_kernel<<<dim3(kB), dim3(1024), 0, stream>>>(
      xyz, pxx, pxy, pxz, pxo, aabb, out_new_xyz);
  ball_query_kernel<<<dim3(kB * kS / 4), dim3(256), 0, stream>>>(
      xyz, out_new_xyz, idxbuf);
  group_mlp_kernel<<<dim3(kB * kS / 2), dim3(128), 0, stream>>>(
      xyz, out_new_xyz, featsT, idxbuf,
      w1, b1, w2, b2, w3, b3, wa, ba, wc, bc, aggT, out_scores);
  transpose_kernel<<<dim3(128 / 32, kS / 32, kB), dim3(32, 8, 1), 0, stream>>>(
      aggT, out_feat, kS, 128);
}